// Round 4
// baseline (4127.753 us; speedup 1.0000x reference)
//
#include <hip/hip_runtime.h>
#include <hip/hip_bf16.h>

// ---------------------------------------------------------------------------
// RNN_20572893348005: 2-layer tanh RNN, B=64 T=1024 D=128 H=256, out [B,H,T]
//
// v5: paired-layer MFMA scan with embedded projections.
// One dispatch type (rnn_pair), launched NC+2 times (software pipeline):
//   blocks 0-3 : [embedded proj0 (x @ W_ih0^T + b0, MFMA)] then scan0(c+1)
//   blocks 4-7 : [embedded proj1 (h0 @ W_ih1^T + b1, MFMA)] then scan1(c)
//   blocks 8+  : transpose chunk c-2's h1 -> out [b][j][t]
// Register discipline: all MFMA operands (A-frags, B-frags, acc) go through
// "v"-constrained inline asm so RA must keep them in arch VGPRs (v4's builtin
// path homed A in AGPRs -> per-use v_accvgpr_read tax, VGPR_Count=56,
// 3458 cy/step). Hazards: s_nop 1 per MFMA (VALU->src), s_nop 7 x3 fence
// before acc readout (>=18 wait states).
// Scan core layouts identical to v4 (correctness-validated):
//   A: lane holds A[RT+(lane&15)][ks*32+(lane>>4)*8+i]
//   B: lane holds B[ks*32+(lane>>4)*8+i][lane&15]   (Bbuf row = batch)
//   D: lane holds D[RT+4*(lane>>4)+r][lane&15]
// ---------------------------------------------------------------------------

#define B_ 64
#define T_ 1024
#define D_ 128
#define H_ 256

typedef _Float16 f16x8 __attribute__((ext_vector_type(8)));
typedef float f32x4 __attribute__((ext_vector_type(4)));

__device__ __forceinline__ float bf2f(unsigned short u) {
    union { unsigned int i; float f; } v;
    v.i = ((unsigned int)u) << 16;
    return v.f;
}

__device__ __forceinline__ unsigned int cvt2_bf16_to_f16(unsigned int u) {
    union { float f; unsigned int i; } a, b;
    a.i = u << 16;
    b.i = u & 0xFFFF0000u;
    union { _Float16 h[2]; unsigned int u; } r;
    r.h[0] = (_Float16)a.f;
    r.h[1] = (_Float16)b.f;
    return r.u;
}

__device__ __forceinline__ uint4 cvt8_bf16_to_f16(uint4 v) {
    uint4 r;
    r.x = cvt2_bf16_to_f16(v.x);
    r.y = cvt2_bf16_to_f16(v.y);
    r.z = cvt2_bf16_to_f16(v.z);
    r.w = cvt2_bf16_to_f16(v.w);
    return r;
}

// branch-free tanh: (e^{2x}-1)/(e^{2x}+1) via exp2 + rcp; saturates correctly.
__device__ __forceinline__ float fast_tanh(float x) {
#if defined(__HIP_DEVICE_COMPILE__) && __has_builtin(__builtin_amdgcn_exp2f)
    float e = __builtin_amdgcn_exp2f(x * 2.885390081777927f);
#else
    float e = __expf(2.0f * x);
#endif
#if defined(__HIP_DEVICE_COMPILE__) && __has_builtin(__builtin_amdgcn_rcpf)
    return 1.0f - 2.0f * __builtin_amdgcn_rcpf(e + 1.0f);
#else
    return 1.0f - 2.0f / (e + 1.0f);
#endif
}

// MFMA through inline asm: forces A/B/acc into arch VGPRs (no AGPR moves).
// s_nop 1 = 2 wait states covers VALU-write -> MFMA-src-read hazard.
__device__ __forceinline__ void mfma16(f32x4& acc, f16x8 a, f16x8 b) {
    asm volatile("s_nop 1\n\tv_mfma_f32_16x16x32_f16 %0, %1, %2, %0"
                 : "+v"(acc) : "v"(a), "v"(b));
}
// >=18 wait states between last MFMA and VALU reads of acc.
__device__ __forceinline__ void mfma_fence(f32x4& a0, f32x4& a1) {
    asm volatile("s_nop 7\n\ts_nop 7\n\ts_nop 7" : "+v"(a0), "+v"(a1));
}

// ---- dtype detection ------------------------------------------------------
__global__ void detect_dtype(const unsigned short* __restrict__ w, int* __restrict__ flag) {
    if (threadIdx.x == 0 && blockIdx.x == 0) {
        int f = 0;
        for (int i = 0; i < 512; ++i) {
            unsigned e = (w[i] >> 7) & 0xFF;
            if (e >= 127) f = 1;
        }
        *flag = f;
    }
}

// ---- prep: weights (bf16|f32) -> f16, bias sums -> f32, zero carries -----
__global__ void prep_w(const void* __restrict__ wih0, const void* __restrict__ whh0,
                       const void* __restrict__ bih0, const void* __restrict__ bhh0,
                       const void* __restrict__ wih1, const void* __restrict__ whh1,
                       const void* __restrict__ bih1, const void* __restrict__ bhh1,
                       _Float16* __restrict__ owih0, _Float16* __restrict__ owhh0,
                       _Float16* __restrict__ owih1, _Float16* __restrict__ owhh1,
                       float* __restrict__ obias0, float* __restrict__ obias1,
                       uint4* __restrict__ carries, const int* __restrict__ flag) {
    const bool f32 = (*flag != 0);
    int i = blockIdx.x * 256 + threadIdx.x;
    auto rd = [&](const void* p, int idx) -> float {
        return f32 ? ((const float*)p)[idx] : bf2f(((const unsigned short*)p)[idx]);
    };
    if (i < H_ * D_) owih0[i] = (_Float16)rd(wih0, i);
    if (i < H_ * H_) {
        owhh0[i] = (_Float16)rd(whh0, i);
        owih1[i] = (_Float16)rd(wih1, i);
        owhh1[i] = (_Float16)rd(whh1, i);
    }
    if (i < H_) {
        obias0[i] = rd(bih0, i) + rd(bhh0, i);
        obias1[i] = rd(bih1, i) + rd(bhh1, i);
    }
    if (i < (2 * B_ * H_) / 8) carries[i] = uint4{0, 0, 0, 0};
}

// ---- embedded projection: outx[b][t][:] = src_row(b,t) @ W^T + bias ------
// One scan-WG (512 thr, 16 batches b0..b0+15); wave wv owns rows [32wv,32wv+32).
// Stores exactly the 8B words the same lane later reads in scan_run.
template <int K, bool XSRC>
__device__ __forceinline__ void proj_embed(
    const void* __restrict__ src, const _Float16* __restrict__ W,
    const float* __restrict__ bias, _Float16* __restrict__ outx,
    int b0, int t0, int Tc, bool f32src, int tid)
{
    constexpr int NKS = K / 32;
    const int wv = tid >> 6, lane = tid & 63;
    const int col = lane & 15, g = lane >> 4;
    const int R0 = wv * 32;

    f16x8 Ap0[NKS], Ap1[NKS];
#pragma unroll
    for (int ks = 0; ks < NKS; ++ks) {
        Ap0[ks] = *(const f16x8*)(W + (long)(R0 + col) * K + ks * 32 + g * 8);
        Ap1[ks] = *(const f16x8*)(W + (long)(R0 + 16 + col) * K + ks * 32 + g * 8);
        asm volatile("" : "+v"(Ap0[ks]), "+v"(Ap1[ks]));
    }
    union { uint4 u; float f[4]; } bb0, bb1;
    bb0.u = *(const uint4*)(bias + R0 + 4 * g);
    bb1.u = *(const uint4*)(bias + R0 + 16 + 4 * g);

    const long brow = (long)(b0 + col);
#pragma unroll 1
    for (int t = 0; t < Tc; ++t) {
        f16x8 Bf[NKS];
        if (XSRC) {
            const long rb = (brow * T_ + t0 + t) * (long)K;
            if (f32src) {
#pragma unroll
                for (int ks = 0; ks < NKS; ++ks) {
                    const float* s = (const float*)src + rb + ks * 32 + g * 8;
                    float4 lo = *(const float4*)s, hi = *(const float4*)(s + 4);
                    union { _Float16 h[8]; f16x8 v; } r8;
                    r8.h[0] = (_Float16)lo.x; r8.h[1] = (_Float16)lo.y;
                    r8.h[2] = (_Float16)lo.z; r8.h[3] = (_Float16)lo.w;
                    r8.h[4] = (_Float16)hi.x; r8.h[5] = (_Float16)hi.y;
                    r8.h[6] = (_Float16)hi.z; r8.h[7] = (_Float16)hi.w;
                    Bf[ks] = r8.v;
                }
            } else {
#pragma unroll
                for (int ks = 0; ks < NKS; ++ks) {
                    uint4 u = *(const uint4*)((const unsigned short*)src + rb + ks * 32 + g * 8);
                    union { uint4 u4; f16x8 v; } cc; cc.u4 = cvt8_bf16_to_f16(u);
                    Bf[ks] = cc.v;
                }
            }
        } else {
            const long rb = (brow * Tc + t) * (long)H_;
#pragma unroll
            for (int ks = 0; ks < NKS; ++ks)
                Bf[ks] = *(const f16x8*)((const _Float16*)src + rb + ks * 32 + g * 8);
        }
        f32x4 a0 = {0.f, 0.f, 0.f, 0.f}, a1 = {0.f, 0.f, 0.f, 0.f};
#pragma unroll
        for (int ks = 0; ks < NKS; ++ks) {
            mfma16(a0, Ap0[ks], Bf[ks]);
            mfma16(a1, Ap1[ks], Bf[ks]);
        }
        mfma_fence(a0, a1);
        _Float16* op = outx + (brow * Tc + t) * (long)H_ + R0 + 4 * g;
        union { _Float16 h[4]; uint2 u; } p0, p1;
#pragma unroll
        for (int r = 0; r < 4; ++r) {
            p0.h[r] = (_Float16)(a0[r] + bb0.f[r]);
            p1.h[r] = (_Float16)(a1[r] + bb1.f[r]);
        }
        *(uint2*)op = p0.u;
        *(uint2*)(op + 16) = p1.u;
    }
}

// ---- MFMA recurrence scan: h[t] = tanh(Whh h[t-1] + xw[t]) ---------------
// v4 core, asm-MFMA operands. 512 thr, 16 batches, 8 waves x 32 rows.
__device__ __forceinline__ void scan_run(
    const _Float16* __restrict__ xw, const _Float16* __restrict__ Whh,
    _Float16* __restrict__ carry, _Float16* __restrict__ outh,
    char* __restrict__ sm, int b0, int tid, int Tc)
{
    const int wv = tid >> 6, lane = tid & 63;
    const int col = lane & 15, g = lane >> 4;
    const int R0 = wv * 32;
    const int swz = (col & 7) << 4;

    f16x8 A0[8], A1[8];
#pragma unroll
    for (int ks = 0; ks < 8; ++ks) {
        A0[ks] = *(const f16x8*)(Whh + (long)(R0 + col) * H_ + ks * 32 + g * 8);
        A1[ks] = *(const f16x8*)(Whh + (long)(R0 + 16 + col) * H_ + ks * 32 + g * 8);
        asm volatile("" : "+v"(A0[ks]), "+v"(A1[ks]));
    }

    // init Bbuf[0] from carry: 512 thr = 16 rows x 32 slots (16B, swizzled)
    {
        const int rr = tid >> 5, s = tid & 31;
        uint4 v = *(const uint4*)(carry + (long)(b0 + rr) * H_ + s * 8);
        *(uint4*)(sm + rr * 512 + ((s ^ (rr & 7)) << 4)) = v;
    }
    __syncthreads();

    const long xrow = (long)(b0 + col) * Tc;
    const int j0a = R0 + 4 * g, j0b = R0 + 16 + 4 * g;
    uint2 pendA = {0, 0}, pendB = {0, 0};
    uint2 xwcA = *(const uint2*)(xw + xrow * (long)H_ + j0a);
    uint2 xwcB = *(const uint2*)(xw + xrow * (long)H_ + j0b);

#pragma unroll 1
    for (int it = 0; it < Tc; ++it) {
        const int p = it & 1;
        if (it > 0) {  // delayed store: retires under this step's MFMAs
            _Float16* op = outh + (xrow + (it - 1)) * (long)H_;
            *(uint2*)(op + j0a) = pendA;
            *(uint2*)(op + j0b) = pendB;
        }
        uint2 xwnA = xwcA, xwnB = xwcB;
        if (it + 1 < Tc) {  // next-step xw prefetch (L2-local: same WG wrote it)
            const _Float16* np = xw + (xrow + it + 1) * (long)H_;
            xwnA = *(const uint2*)(np + j0a);
            xwnB = *(const uint2*)(np + j0b);
        }
        f32x4 a0 = {0.f, 0.f, 0.f, 0.f}, a1 = {0.f, 0.f, 0.f, 0.f};
        const char* rb = sm + (p * 16 + col) * 512;
#pragma unroll
        for (int ks = 0; ks < 8; ++ks) {
            union { uint4 u; f16x8 v; } bf;
            bf.u = *(const uint4*)(rb + (((ks * 4 + g) << 4) ^ swz));
            mfma16(a0, A0[ks], bf.v);
            mfma16(a1, A1[ks], bf.v);
        }
        mfma_fence(a0, a1);
        char* wb = sm + ((p ^ 1) * 16 + col) * 512;
        union { uint2 u; _Float16 h[4]; } xA, xB; xA.u = xwcA; xB.u = xwcB;
        union { _Float16 h[4]; uint2 u; } pA, pB;
#pragma unroll
        for (int r = 0; r < 4; ++r) {
            pA.h[r] = (_Float16)fast_tanh(a0[r] + (float)xA.h[r]);
            pB.h[r] = (_Float16)fast_tanh(a1[r] + (float)xB.h[r]);
        }
        *(uint2*)(wb + (((j0a >> 3) << 4) ^ swz) + ((j0a << 1) & 15)) = pA.u;
        *(uint2*)(wb + (((j0b >> 3) << 4) ^ swz) + ((j0b << 1) & 15)) = pB.u;
        pendA = pA.u; pendB = pB.u;
        xwcA = xwnA; xwcB = xwnB;
        __syncthreads();
    }

    _Float16* op = outh + (xrow + (Tc - 1)) * (long)H_;
    *(uint2*)(op + j0a) = pendA;
    *(uint2*)(op + j0b) = pendB;
    *(uint2*)(carry + (long)(b0 + col) * H_ + j0a) = pendA;
    *(uint2*)(carry + (long)(b0 + col) * H_ + j0b) = pendB;
}

// ---- paired dispatch: scan0(c+1) || scan1(c) || transpose(c-1... c-2) ----
__global__ __launch_bounds__(512, 2) void rnn_pair(
    const void* __restrict__ x,
    const _Float16* __restrict__ Wih0, const _Float16* __restrict__ Whh0,
    const _Float16* __restrict__ Wih1, const _Float16* __restrict__ Whh1,
    const float* __restrict__ bias0, const float* __restrict__ bias1,
    _Float16* __restrict__ carry0, _Float16* __restrict__ carry1,
    _Float16* __restrict__ xw0g, _Float16* __restrict__ xw1g,
    const _Float16* __restrict__ h0in, _Float16* __restrict__ h0out,
    const _Float16* __restrict__ h1prev, _Float16* __restrict__ h1out,
    void* __restrict__ dout, const int* __restrict__ flag,
    int t0A, int t0B, int t0T, int Tc)
{
    __shared__ __align__(16) char sm[16640];  // max(scan Bbuf 16384, tile 16640)
    const int bid = blockIdx.x;
    const int tid = threadIdx.x;

    if (bid < 8) {
        const bool is0 = bid < 4;
        const int t0 = is0 ? t0A : t0B;
        if (t0 < 0) return;
        const int b0 = (bid & 3) * 16;
        if (is0) {
            proj_embed<D_, true>(x, Wih0, bias0, xw0g, b0, t0, Tc, (*flag != 0), tid);
            __threadfence_block();
            __syncthreads();
            scan_run(xw0g, Whh0, carry0, h0out, sm, b0, tid, Tc);
        } else {
            proj_embed<H_, false>(h0in, Wih1, bias1, xw1g, b0, t0, Tc, false, tid);
            __threadfence_block();
            __syncthreads();
            scan_run(xw1g, Whh1, carry1, h1out, sm, b0, tid, Tc);
        }
    } else {
        if (t0T < 0) return;
        const int nTc = (Tc + 63) >> 6;
        int b2 = bid - 8;
        const int jblk = b2 & 3; b2 >>= 2;   // H_/64 == 4
        const int tcblk = b2 % nTc;
        const int b = b2 / nTc;
        const bool f32o = (*flag != 0);
        float* tile = (float*)sm;            // [64][65]
#pragma unroll
        for (int k = 0; k < 8; ++k) {
            int idx = k * 512 + tid;
            int r = idx >> 6, c = idx & 63;
            int tc = tcblk * 64 + r;
            tile[r * 65 + c] = (tc < Tc)
                ? (float)h1prev[((long)b * Tc + tc) * H_ + jblk * 64 + c] : 0.f;
        }
        __syncthreads();
#pragma unroll
        for (int k = 0; k < 8; ++k) {
            int idx = k * 512 + tid;
            int jr = idx >> 6, tc = idx & 63;
            if (tcblk * 64 + tc < Tc) {
                float v = tile[tc * 65 + jr];
                long o = ((long)b * H_ + jblk * 64 + jr) * (long)T_ + t0T + tcblk * 64 + tc;
                if (f32o) ((float*)dout)[o] = v;
                else      ((__hip_bfloat16*)dout)[o] = __float2bfloat16(v);
            }
        }
    }
}

// ---------------------------------------------------------------------------
extern "C" void kernel_launch(void* const* d_in, const int* in_sizes, int n_in,
                              void* d_out, int out_size, void* d_ws, size_t ws_size,
                              hipStream_t stream) {
    const void* x    = d_in[0];
    const void* wih0 = d_in[1];
    const void* whh0 = d_in[2];
    const void* bih0 = d_in[3];
    const void* bhh0 = d_in[4];
    const void* wih1 = d_in[5];
    const void* whh1 = d_in[6];
    const void* bih1 = d_in[7];
    const void* bhh1 = d_in[8];
    (void)in_sizes; (void)n_in; (void)out_size;

    char* ws = (char*)d_ws;
    size_t off = 0;
    auto alloc = [&](size_t bytes) -> void* {
        void* p = ws + off;
        off += (bytes + 255) & ~(size_t)255;
        return p;
    };

    int*      flag    = (int*)alloc(256);
    _Float16* wih0_16 = (_Float16*)alloc((size_t)H_ * D_ * 2);
    _Float16* whh0_16 = (_Float16*)alloc((size_t)H_ * H_ * 2);
    _Float16* wih1_16 = (_Float16*)alloc((size_t)H_ * H_ * 2);
    _Float16* whh1_16 = (_Float16*)alloc((size_t)H_ * H_ * 2);
    float*    bias0   = (float*)alloc(H_ * 4);
    float*    bias1   = (float*)alloc(H_ * 4);
    _Float16* carry0  = (_Float16*)alloc((size_t)B_ * H_ * 2);
    _Float16* carry1  = (_Float16*)alloc((size_t)B_ * H_ * 2);
    size_t fixed = off;

    // largest chunk Tc whose SIX chunk buffers fit (xw0g, xw1g, h0g x2, h1g x2)
    int Tc = 256;
    while (Tc > 32 && fixed + 6 * ((size_t)B_ * Tc * H_ * 2 + 256) > ws_size) Tc >>= 1;
    _Float16* xw0g = (_Float16*)alloc((size_t)B_ * Tc * H_ * 2);
    _Float16* xw1g = (_Float16*)alloc((size_t)B_ * Tc * H_ * 2);
    _Float16* h0g[2], * h1g[2];
    h0g[0] = (_Float16*)alloc((size_t)B_ * Tc * H_ * 2);
    h0g[1] = (_Float16*)alloc((size_t)B_ * Tc * H_ * 2);
    h1g[0] = (_Float16*)alloc((size_t)B_ * Tc * H_ * 2);
    h1g[1] = (_Float16*)alloc((size_t)B_ * Tc * H_ * 2);

    detect_dtype<<<1, 64, 0, stream>>>((const unsigned short*)whh0, flag);
    prep_w<<<(H_ * H_ + 255) / 256, 256, 0, stream>>>(
        wih0, whh0, bih0, bhh0, wih1, whh1, bih1, bhh1,
        wih0_16, whh0_16, wih1_16, whh1_16, bias0, bias1, (uint4*)carry0, flag);

    const int NC  = T_ / Tc;
    const int nTc = (Tc + 63) / 64;
    const int NT  = B_ * nTc * (H_ / 64);
    for (int d = 0; d <= NC + 1; ++d) {
        const int cA = d, cB = d - 1, cT = d - 2;
        const int t0A = (cA <= NC - 1) ? cA * Tc : -1;
        const int t0B = (cB >= 0 && cB <= NC - 1) ? cB * Tc : -1;
        const int t0T = (cT >= 0) ? cT * Tc : -1;
        rnn_pair<<<8 + NT, 512, 0, stream>>>(
            x, wih0_16, whh0_16, wih1_16, whh1_16, bias0, bias1,
            carry0, carry1, xw0g, xw1g,
            h0g[cB & 1],        // h0in  (chunk cB, written last dispatch)
            h0g[cA & 1],        // h0out (chunk cA)
            h1g[cT & 1],        // h1prev (chunk cT)
            h1g[cB & 1],        // h1out (chunk cB)
            d_out, flag, t0A, t0B, t0T, Tc);
    }
}

// Round 5
// 2326.787 us; speedup vs baseline: 1.7740x; 1.7740x over previous
//
#include <hip/hip_runtime.h>
#include <hip/hip_bf16.h>

// ---------------------------------------------------------------------------
// RNN_20572893348005: 2-layer tanh RNN, B=64 T=1024 D=128 H=256, out [B,H,T]
//
// v6: pipelined mega-dispatch, MFMA scan with raw barriers.
// Dispatch d (one kernel, block ranges; all cross-role deps span dispatches):
//   blocks 0-3     : scan0 chunk d        (xw0 from dispatch d-1's proj0)
//   blocks 4-7     : scan1 chunk d-2      (xw1 from dispatch d-1's proj1)
//   blocks 8..     : proj0 chunk d+1      (parallel dot2 GEMM, proven v1 code)
//   blocks ..      : proj1 chunk d-1      (reads h0 from dispatch d-1's scan0)
//   blocks ..      : transpose chunk d-3  (reads h1 from dispatch d-1's scan1)
// Scan fixes vs v4 (3458 cy/step):
//   - 4 waves x NTILE=4 (64 rows/wave): halves the per-step LDS B-panel
//     re-read (64KB -> 32KB/CU) - the dominant throughput term.
//   - raw `s_waitcnt lgkmcnt(0); s_barrier` (asm) instead of __syncthreads():
//     no vmcnt(0) drain per step; delayed global h-store floats across
//     barriers; compiler's counted vmcnt covers the xw prefetch at use.
//   - builtin MFMA again: AGPR-homed A-fragments are free as MFMA sources
//     (unified file) - v5 disproved the "force arch VGPRs" theory.
// ---------------------------------------------------------------------------

#define B_ 64
#define T_ 1024
#define D_ 128
#define H_ 256

typedef _Float16 half2_t __attribute__((ext_vector_type(2)));
typedef _Float16 f16x8 __attribute__((ext_vector_type(8)));
typedef float f32x4 __attribute__((ext_vector_type(4)));

__device__ __forceinline__ float bf2f(unsigned short u) {
    union { unsigned int i; float f; } v;
    v.i = ((unsigned int)u) << 16;
    return v.f;
}

__device__ __forceinline__ unsigned int cvt2_bf16_to_f16(unsigned int u) {
    union { float f; unsigned int i; } a, b;
    a.i = u << 16;
    b.i = u & 0xFFFF0000u;
    union { _Float16 h[2]; unsigned int u; } r;
    r.h[0] = (_Float16)a.f;
    r.h[1] = (_Float16)b.f;
    return r.u;
}

__device__ __forceinline__ uint4 cvt8_bf16_to_f16(uint4 v) {
    uint4 r;
    r.x = cvt2_bf16_to_f16(v.x);
    r.y = cvt2_bf16_to_f16(v.y);
    r.z = cvt2_bf16_to_f16(v.z);
    r.w = cvt2_bf16_to_f16(v.w);
    return r;
}

__device__ __forceinline__ float dot2(unsigned int a, unsigned int b, float c) {
    union { unsigned int u; half2_t h; } ua, ub;
    ua.u = a; ub.u = b;
#if defined(__HIP_DEVICE_COMPILE__) && __has_builtin(__builtin_amdgcn_fdot2)
    return __builtin_amdgcn_fdot2(ua.h, ub.h, c, false);
#else
    return c + (float)ua.h.x * (float)ub.h.x + (float)ua.h.y * (float)ub.h.y;
#endif
}

// branch-free tanh: (e^{2x}-1)/(e^{2x}+1) via exp2 + rcp; saturates correctly.
__device__ __forceinline__ float fast_tanh(float x) {
#if defined(__HIP_DEVICE_COMPILE__) && __has_builtin(__builtin_amdgcn_exp2f)
    float e = __builtin_amdgcn_exp2f(x * 2.885390081777927f);
#else
    float e = __expf(2.0f * x);
#endif
#if defined(__HIP_DEVICE_COMPILE__) && __has_builtin(__builtin_amdgcn_rcpf)
    return 1.0f - 2.0f * __builtin_amdgcn_rcpf(e + 1.0f);
#else
    return 1.0f - 2.0f / (e + 1.0f);
#endif
}

// raw workgroup barrier: LDS ordering only (no vmcnt drain).
__device__ __forceinline__ void lds_barrier() {
    asm volatile("s_waitcnt lgkmcnt(0)\n\ts_barrier" ::: "memory");
}

// ---- dtype detection ------------------------------------------------------
__global__ void detect_dtype(const unsigned short* __restrict__ w, int* __restrict__ flag) {
    if (threadIdx.x == 0 && blockIdx.x == 0) {
        int f = 0;
        for (int i = 0; i < 512; ++i) {
            unsigned e = (w[i] >> 7) & 0xFF;
            if (e >= 127) f = 1;
        }
        *flag = f;
    }
}

// ---- prep: weights (bf16|f32) -> f16, bias sums -> f32, zero carries -----
__global__ void prep_w(const void* __restrict__ wih0, const void* __restrict__ whh0,
                       const void* __restrict__ bih0, const void* __restrict__ bhh0,
                       const void* __restrict__ wih1, const void* __restrict__ whh1,
                       const void* __restrict__ bih1, const void* __restrict__ bhh1,
                       _Float16* __restrict__ owih0, _Float16* __restrict__ owhh0,
                       _Float16* __restrict__ owih1, _Float16* __restrict__ owhh1,
                       float* __restrict__ obias0, float* __restrict__ obias1,
                       uint4* __restrict__ carries, const int* __restrict__ flag) {
    const bool f32 = (*flag != 0);
    int i = blockIdx.x * 256 + threadIdx.x;
    auto rd = [&](const void* p, int idx) -> float {
        return f32 ? ((const float*)p)[idx] : bf2f(((const unsigned short*)p)[idx]);
    };
    if (i < H_ * D_) owih0[i] = (_Float16)rd(wih0, i);
    if (i < H_ * H_) {
        owhh0[i] = (_Float16)rd(whh0, i);
        owih1[i] = (_Float16)rd(wih1, i);
        owhh1[i] = (_Float16)rd(whh1, i);
    }
    if (i < H_) {
        obias0[i] = rd(bih0, i) + rd(bhh0, i);
        obias1[i] = rd(bih1, i) + rd(bhh1, i);
    }
    if (i < (2 * B_ * H_) / 8) carries[i] = uint4{0, 0, 0, 0};
}

// ---- projection device fn (v1/v4 proven code): 16 rows per pseudo-block --
template <int K, bool SRCX>
__device__ __forceinline__ void proj_dev(const void* __restrict__ A,
                                         const _Float16* __restrict__ W,
                                         const float* __restrict__ bias,
                                         _Float16* __restrict__ outx,
                                         const int* __restrict__ flag,
                                         int t0, int Tc, int pb,
                                         char* __restrict__ sm, int tid) {
    constexpr int KW = K / 8;  // uint4 (8 f16) per row
    const int j = tid;
    const long m0 = (long)pb * 16;
    const bool f32 = SRCX && (*flag != 0);

    long arow0;
    if (SRCX) {
        long b = m0 / Tc;
        long tc0 = m0 - b * Tc;
        arow0 = (b * T_ + t0 + tc0) * (long)K;
    } else {
        arow0 = m0 * (long)K;
    }

    uint4 w[KW];
    const uint4* wp = (const uint4*)(W + (long)j * K);
#pragma unroll
    for (int i = 0; i < KW; ++i) w[i] = wp[i];

    uint4* xt = (uint4*)sm;  // 16*KW uint4 (<= 8KB)
    for (int i = tid; i < 16 * KW; i += 256) {
        int r = i / KW, c = i % KW;
        long off = arow0 + (long)r * K + (long)c * 8;  // element offset
        if (SRCX) {
            if (f32) {
                const float* s = (const float*)A + off;
                union { _Float16 h[8]; uint4 u; } r8;
#pragma unroll
                for (int q = 0; q < 8; ++q) r8.h[q] = (_Float16)s[q];
                xt[i] = r8.u;
            } else {
                xt[i] = cvt8_bf16_to_f16(*(const uint4*)((const unsigned short*)A + off));
            }
        } else {
            xt[i] = *(const uint4*)((const _Float16*)A + off);
        }
    }
    __syncthreads();

    const float bb = bias[j];
#pragma unroll 1
    for (int r = 0; r < 16; ++r) {
        const uint4* xr = xt + r * KW;
        float a0 = 0.f, a1 = 0.f, a2 = 0.f, a3 = 0.f;
#pragma unroll
        for (int i = 0; i < KW; ++i) {
            uint4 h = xr[i];   // wave-uniform LDS broadcast
            uint4 ww = w[i];
            a0 = dot2(ww.x, h.x, a0);
            a1 = dot2(ww.y, h.y, a1);
            a2 = dot2(ww.z, h.z, a2);
            a3 = dot2(ww.w, h.w, a3);
        }
        outx[(m0 + r) * H_ + j] = (_Float16)(((a0 + a1) + (a2 + a3)) + bb);
    }
}

// ---- MFMA recurrence scan: h[t] = tanh(Whh h[t-1] + xw[t]) ---------------
// 256 thr = 4 waves x NTILE=4 (64 rows/wave), 16 batches. Fragment layouts
// validated in v3/v4:
//   A: lane holds A[R+ (lane&15)][ks*32+(lane>>4)*8+i]
//   B: lane holds B[ks*32+(lane>>4)*8+i][lane&15]   (Bbuf row = batch)
//   D: lane holds D[R+4*(lane>>4)+r][lane&15]
// LDS Bbuf rows 512B, 16B slots XOR-swizzled by (row&7).
__device__ __forceinline__ void scan_dev(
    const _Float16* __restrict__ xw,    // [16b][Tc][H] at b0
    const _Float16* __restrict__ Whh,   // [256][256] f16
    _Float16* __restrict__ carry,       // [B][H]
    _Float16* __restrict__ outh,        // [16b][Tc][H] at b0
    char* __restrict__ sm, int b0, int tid, int Tc)
{
    const int wv = tid >> 6, lane = tid & 63;
    const int col = lane & 15, g = lane >> 4;
    const int R0 = wv * 64;
    const int swz = (col & 7) << 4;

    f16x8 A[4][8];   // 128 regs (VGPR or AGPR - both free as MFMA sources)
#pragma unroll
    for (int tt = 0; tt < 4; ++tt)
#pragma unroll
        for (int ks = 0; ks < 8; ++ks)
            A[tt][ks] = *(const f16x8*)(Whh + (long)(R0 + tt * 16 + col) * H_ + ks * 32 + g * 8);

    // init Bbuf[0] from carry: 512 (row,slot) pairs over 256 threads
    for (int i = tid; i < 512; i += 256) {
        int rr = i >> 5, s = i & 31;
        uint4 v = *(const uint4*)(carry + (long)(b0 + rr) * H_ + s * 8);
        *(uint4*)(sm + rr * 512 + ((s ^ (rr & 7)) << 4)) = v;
    }
    lds_barrier();

    const long xrow = (long)(b0 + col) * Tc;
    int j0[4];
    uint2 pend[4], xwc[4], xwn[4];
#pragma unroll
    for (int tt = 0; tt < 4; ++tt) {
        j0[tt] = R0 + tt * 16 + 4 * g;
        xwc[tt] = *(const uint2*)(xw + xrow * H_ + j0[tt]);
    }

#pragma unroll 1
    for (int it = 0; it < Tc; ++it) {
        const int p = it & 1;
        // next-step xw prefetch (consumed in NEXT iteration's epilogue;
        // compiler's counted vmcnt waits at the use, not here)
        if (it + 1 < Tc) {
#pragma unroll
            for (int tt = 0; tt < 4; ++tt)
                xwn[tt] = *(const uint2*)(xw + (xrow + it + 1) * H_ + j0[tt]);
        }
        // delayed global h-store: floats across the raw barrier (no drain)
        if (it > 0) {
            _Float16* op = outh + (xrow + it - 1) * H_;
#pragma unroll
            for (int tt = 0; tt < 4; ++tt) *(uint2*)(op + j0[tt]) = pend[tt];
        }
        // MFMA block: 8 k-slices, shared B-frag, 4 independent accumulators
        f32x4 a0 = {0.f,0.f,0.f,0.f}, a1 = {0.f,0.f,0.f,0.f};
        f32x4 a2 = {0.f,0.f,0.f,0.f}, a3 = {0.f,0.f,0.f,0.f};
        const char* rb = sm + (p * 16 + col) * 512;
#pragma unroll
        for (int ks = 0; ks < 8; ++ks) {
            union { uint4 u; f16x8 v; } bf;
            bf.u = *(const uint4*)(rb + (((ks * 4 + g) << 4) ^ swz));
            a0 = __builtin_amdgcn_mfma_f32_16x16x32_f16(A[0][ks], bf.v, a0, 0, 0, 0);
            a1 = __builtin_amdgcn_mfma_f32_16x16x32_f16(A[1][ks], bf.v, a1, 0, 0, 0);
            a2 = __builtin_amdgcn_mfma_f32_16x16x32_f16(A[2][ks], bf.v, a2, 0, 0, 0);
            a3 = __builtin_amdgcn_mfma_f32_16x16x32_f16(A[3][ks], bf.v, a3, 0, 0, 0);
        }
        // epilogue: tanh + pack, write new h to Bbuf[p^1]
        char* wb = sm + ((p ^ 1) * 16 + col) * 512;
#define EPI(tt, av)                                                            \
        {                                                                      \
            union { uint2 u; _Float16 h[4]; } xv; xv.u = xwc[tt];              \
            union { _Float16 h[4]; uint2 u; } pk;                              \
            pk.h[0] = (_Float16)fast_tanh(av[0] + (float)xv.h[0]);             \
            pk.h[1] = (_Float16)fast_tanh(av[1] + (float)xv.h[1]);             \
            pk.h[2] = (_Float16)fast_tanh(av[2] + (float)xv.h[2]);             \
            pk.h[3] = (_Float16)fast_tanh(av[3] + (float)xv.h[3]);             \
            *(uint2*)(wb + (((j0[tt] >> 3) << 4) ^ swz) + ((j0[tt] << 1) & 15)) = pk.u; \
            pend[tt] = pk.u;                                                   \
        }
        EPI(0, a0) EPI(1, a1) EPI(2, a2) EPI(3, a3)
#undef EPI
#pragma unroll
        for (int tt = 0; tt < 4; ++tt) xwc[tt] = xwn[tt];
        lds_barrier();
    }

    _Float16* op = outh + (xrow + Tc - 1) * H_;
#pragma unroll
    for (int tt = 0; tt < 4; ++tt) {
        *(uint2*)(op + j0[tt]) = pend[tt];
        *(uint2*)(carry + (long)(b0 + col) * H_ + j0[tt]) = pend[tt];
    }
}

// ---- transpose device fn: tmp [b][tc][j] f16 -> out [b][j][t0+tc] --------
__device__ __forceinline__ void transpose_dev(
    const _Float16* __restrict__ tmp, void* __restrict__ out,
    const int* __restrict__ flag, int t0, int Tc, int pb,
    char* __restrict__ sm, int tid)
{
    const int nTc = (Tc + 63) >> 6;
    int bid = pb;
    const int jblk = bid & 3; bid >>= 2;           // H_/64 == 4
    const int tcblk = bid % nTc;
    const int b = bid / nTc;
    const bool f32o = (*flag != 0);
    float* tile = (float*)sm;                      // [64][65]
#pragma unroll
    for (int k = 0; k < 16; ++k) {
        int idx = k * 256 + tid;
        int r = idx >> 6, c = idx & 63;
        int tc = tcblk * 64 + r;
        tile[r * 65 + c] = (tc < Tc)
            ? (float)tmp[((long)b * Tc + tc) * H_ + jblk * 64 + c] : 0.f;
    }
    __syncthreads();
#pragma unroll
    for (int k = 0; k < 16; ++k) {
        int idx = k * 256 + tid;
        int jr = idx >> 6, tc = idx & 63;
        if (tcblk * 64 + tc < Tc) {
            float v = tile[tc * 65 + jr];
            long o = ((long)b * H_ + jblk * 64 + jr) * (long)T_ + t0 + tcblk * 64 + tc;
            if (f32o) ((float*)out)[o] = v;
            else      ((__hip_bfloat16*)out)[o] = __float2bfloat16(v);
        }
    }
}

// ---- boot kernel: proj0 of chunk 0 ---------------------------------------
__global__ __launch_bounds__(256, 1) void proj0_boot(
    const void* __restrict__ x, const _Float16* __restrict__ W,
    const float* __restrict__ bias, _Float16* __restrict__ outx,
    const int* __restrict__ flag, int Tc)
{
    __shared__ __align__(16) char sm[8192];
    proj_dev<D_, true>(x, W, bias, outx, flag, 0, Tc, blockIdx.x, sm, threadIdx.x);
}

// ---- mega dispatch: scan0(d) || scan1(d-2) || proj0(d+1) || proj1(d-1) ---
//      || transpose(d-3).  All cross-role deps span dispatch boundaries.
__global__ __launch_bounds__(256, 1) void mega(
    const void* __restrict__ x,
    const _Float16* __restrict__ Wih0, const _Float16* __restrict__ Whh0,
    const _Float16* __restrict__ Wih1, const _Float16* __restrict__ Whh1,
    const float* __restrict__ b0v, const float* __restrict__ b1v,
    _Float16* __restrict__ carry0, _Float16* __restrict__ carry1,
    const _Float16* __restrict__ xw0r, _Float16* __restrict__ xw0w,
    _Float16* __restrict__ h0w, const _Float16* __restrict__ h0r,
    _Float16* __restrict__ xw1w, const _Float16* __restrict__ xw1r,
    _Float16* __restrict__ h1w, const _Float16* __restrict__ h1r,
    void* __restrict__ dout, const int* __restrict__ flag,
    int t_s0, int t_p0, int t_p1, int t_ct, int s1_valid,
    int Tc, int nproj)
{
    __shared__ __align__(16) char sm[16640];  // max(scan 16384, transpose 16640)
    const int bid = blockIdx.x;
    const int tid = threadIdx.x;

    if (bid < 4) {                       // scan0 chunk d
        if (t_s0 < 0) return;
        scan_dev(xw0r, Whh0, carry0, h0w, sm, bid * 16, tid, Tc);
    } else if (bid < 8) {                // scan1 chunk d-2
        if (!s1_valid) return;
        scan_dev(xw1r, Whh1, carry1, h1w, sm, (bid - 4) * 16, tid, Tc);
    } else if (bid < 8 + nproj) {        // proj0 chunk d+1
        if (t_p0 < 0) return;
        proj_dev<D_, true>(x, Wih0, b0v, xw0w, flag, t_p0, Tc, bid - 8, sm, tid);
    } else if (bid < 8 + 2 * nproj) {    // proj1 chunk d-1
        if (t_p1 < 0) return;
        proj_dev<H_, false>(h0r, Wih1, b1v, xw1w, flag, 0, Tc, bid - 8 - nproj, sm, tid);
    } else {                             // transpose chunk d-3
        if (t_ct < 0) return;
        transpose_dev(h1r, dout, flag, t_ct, Tc, bid - 8 - 2 * nproj, sm, tid);
    }
}

// ---------------------------------------------------------------------------
extern "C" void kernel_launch(void* const* d_in, const int* in_sizes, int n_in,
                              void* d_out, int out_size, void* d_ws, size_t ws_size,
                              hipStream_t stream) {
    const void* x    = d_in[0];
    const void* wih0 = d_in[1];
    const void* whh0 = d_in[2];
    const void* bih0 = d_in[3];
    const void* bhh0 = d_in[4];
    const void* wih1 = d_in[5];
    const void* whh1 = d_in[6];
    const void* bih1 = d_in[7];
    const void* bhh1 = d_in[8];
    (void)in_sizes; (void)n_in; (void)out_size;

    char* ws = (char*)d_ws;
    size_t off = 0;
    auto alloc = [&](size_t bytes) -> void* {
        void* p = ws + off;
        off += (bytes + 255) & ~(size_t)255;
        return p;
    };

    int*      flag    = (int*)alloc(256);
    _Float16* wih0_16 = (_Float16*)alloc((size_t)H_ * D_ * 2);
    _Float16* whh0_16 = (_Float16*)alloc((size_t)H_ * H_ * 2);
    _Float16* wih1_16 = (_Float16*)alloc((size_t)H_ * H_ * 2);
    _Float16* whh1_16 = (_Float16*)alloc((size_t)H_ * H_ * 2);
    float*    bias0   = (float*)alloc(H_ * 4);
    float*    bias1   = (float*)alloc(H_ * 4);
    _Float16* carry0  = (_Float16*)alloc((size_t)B_ * H_ * 2);
    _Float16* carry1  = (_Float16*)alloc((size_t)B_ * H_ * 2);
    size_t fixed = off;

    // largest chunk Tc whose EIGHT chunk buffers fit in ws
    int Tc = 256;
    while (Tc > 32 && fixed + 8 * ((size_t)B_ * Tc * H_ * 2 + 256) > ws_size) Tc >>= 1;
    _Float16 *xw0g[2], *xw1g[2], *h0g[2], *h1g[2];
    for (int i = 0; i < 2; ++i) xw0g[i] = (_Float16*)alloc((size_t)B_ * Tc * H_ * 2);
    for (int i = 0; i < 2; ++i) xw1g[i] = (_Float16*)alloc((size_t)B_ * Tc * H_ * 2);
    for (int i = 0; i < 2; ++i) h0g[i]  = (_Float16*)alloc((size_t)B_ * Tc * H_ * 2);
    for (int i = 0; i < 2; ++i) h1g[i]  = (_Float16*)alloc((size_t)B_ * Tc * H_ * 2);

    detect_dtype<<<1, 64, 0, stream>>>((const unsigned short*)whh0, flag);
    prep_w<<<(H_ * H_ + 255) / 256, 256, 0, stream>>>(
        wih0, whh0, bih0, bhh0, wih1, whh1, bih1, bhh1,
        wih0_16, whh0_16, wih1_16, whh1_16, bias0, bias1, (uint4*)carry0, flag);

    const int NC    = T_ / Tc;
    const int nproj = (B_ * Tc) / 16;
    const int nTc   = (Tc + 63) / 64;
    const int NT    = B_ * nTc * (H_ / 64);
    const int grid  = 8 + 2 * nproj + NT;

    proj0_boot<<<nproj, 256, 0, stream>>>(x, wih0_16, bias0, xw0g[0], flag, Tc);

    for (int d = 0; d <= NC + 2; ++d) {
        const int cs0 = d, cp0 = d + 1, cp1 = d - 1, cs1 = d - 2, cct = d - 3;
        const int t_s0 = (cs0 <= NC - 1) ? cs0 * Tc : -1;
        const int t_p0 = (cp0 <= NC - 1) ? cp0 * Tc : -1;
        const int t_p1 = (cp1 >= 0 && cp1 <= NC - 1) ? cp1 * Tc : -1;
        const int s1v  = (cs1 >= 0 && cs1 <= NC - 1) ? 1 : 0;
        const int t_ct = (cct >= 0 && cct <= NC - 1) ? cct * Tc : -1;
        mega<<<grid, 256, 0, stream>>>(
            x, wih0_16, whh0_16, wih1_16, whh1_16, bias0, bias1,
            carry0, carry1,
            xw0g[cs0 & 1],            // scan0 reads chunk d
            xw0g[cp0 & 1],            // proj0 writes chunk d+1
            h0g[cs0 & 1],             // scan0 writes chunk d
            h0g[cp1 & 1],             // proj1 reads chunk d-1
            xw1g[cp1 & 1],            // proj1 writes chunk d-1
            xw1g[cs1 & 1],            // scan1 reads chunk d-2
            h1g[cs1 & 1],             // scan1 writes chunk d-2
            h1g[cct & 1],             // transpose reads chunk d-3
            d_out, flag, t_s0, t_p0, t_p1, t_ct, s1v, Tc, nproj);
    }
}

// Round 6
// 1508.314 us; speedup vs baseline: 2.7367x; 1.5426x over previous
//
#include <hip/hip_runtime.h>
#include <hip/hip_bf16.h>

// ---------------------------------------------------------------------------
// RNN_20572893348005: 2-layer tanh RNN, B=64 T=1024 D=128 H=256, out [B,H,T]
//
// v7: v2's PROVEN dot2 fused scan (2900 cy/step for both layers — 2.4x better
// per layer than the MFMA scans of v4/v6, which are latency-bound at 3460)
// + v6's PROVEN mega pipelining + two step-latency cuts:
//   (1) xw0 chunk staged in LDS (Tc=128 -> 64KB): ZERO global loads in the
//       sequential loop -> no vmcnt waits / HBM latency on the critical path.
//   (2) raw lgkmcnt-only barrier (v6-proven): per-step h1 global store
//       floats across barriers instead of a vmcnt(0) drain per step.
// Dispatch d: blocks 0-63 fused scan chunk d (1 CU/batch);
//             blocks 64..234 proj0 chunk d+1 (dot2 GEMM, idle CUs);
//             blocks 235+   transpose chunk d-1 -> out [b][j][t].
// All cross-role dependencies span dispatch boundaries (v6-verified pattern).
// ---------------------------------------------------------------------------

#define B_ 64
#define T_ 1024
#define D_ 128
#define H_ 256
#define TC 128                 // time chunk (LDS stage = TC*H*2 = 64 KB)

typedef _Float16 half2_t __attribute__((ext_vector_type(2)));

__device__ __forceinline__ float bf2f(unsigned short u) {
    union { unsigned int i; float f; } v;
    v.i = ((unsigned int)u) << 16;
    return v.f;
}

__device__ __forceinline__ unsigned int cvt2_bf16_to_f16(unsigned int u) {
    union { float f; unsigned int i; } a, b;
    a.i = u << 16;
    b.i = u & 0xFFFF0000u;
    union { _Float16 h[2]; unsigned int u; } r;
    r.h[0] = (_Float16)a.f;
    r.h[1] = (_Float16)b.f;
    return r.u;
}

__device__ __forceinline__ uint4 cvt8_bf16_to_f16(uint4 v) {
    uint4 r;
    r.x = cvt2_bf16_to_f16(v.x);
    r.y = cvt2_bf16_to_f16(v.y);
    r.z = cvt2_bf16_to_f16(v.z);
    r.w = cvt2_bf16_to_f16(v.w);
    return r;
}

__device__ __forceinline__ float dot2(unsigned int a, unsigned int b, float c) {
    union { unsigned int u; half2_t h; } ua, ub;
    ua.u = a; ub.u = b;
#if defined(__HIP_DEVICE_COMPILE__) && __has_builtin(__builtin_amdgcn_fdot2)
    return __builtin_amdgcn_fdot2(ua.h, ub.h, c, false);
#else
    return c + (float)ua.h.x * (float)ub.h.x + (float)ua.h.y * (float)ub.h.y;
#endif
}

// branch-free tanh: (e^{2x}-1)/(e^{2x}+1) via exp2 + rcp; saturates correctly.
__device__ __forceinline__ float fast_tanh(float x) {
#if defined(__HIP_DEVICE_COMPILE__) && __has_builtin(__builtin_amdgcn_exp2f)
    float e = __builtin_amdgcn_exp2f(x * 2.885390081777927f);
#else
    float e = __expf(2.0f * x);
#endif
#if defined(__HIP_DEVICE_COMPILE__) && __has_builtin(__builtin_amdgcn_rcpf)
    return 1.0f - 2.0f * __builtin_amdgcn_rcpf(e + 1.0f);
#else
    return 1.0f - 2.0f / (e + 1.0f);
#endif
}

// raw workgroup barrier: LDS ordering only (no vmcnt drain). v6-proven.
__device__ __forceinline__ void lds_barrier() {
    asm volatile("s_waitcnt lgkmcnt(0)\n\ts_barrier" ::: "memory");
}

// full-row dot product: 256 f16 from LDS (wave-uniform broadcast) . w[32]
__device__ __forceinline__ float dot256(const uint4* __restrict__ w,
                                        const uint4* __restrict__ hb) {
    float a0 = 0.f, a1 = 0.f, a2 = 0.f, a3 = 0.f;
#pragma unroll
    for (int i = 0; i < 32; ++i) {
        uint4 h = hb[i];   // wave-uniform LDS broadcast (conflict-free)
        uint4 ww = w[i];
        a0 = dot2(ww.x, h.x, a0);
        a1 = dot2(ww.y, h.y, a1);
        a2 = dot2(ww.z, h.z, a2);
        a3 = dot2(ww.w, h.w, a3);
    }
    return (a0 + a1) + (a2 + a3);
}

// ---- dtype detection ------------------------------------------------------
__global__ void detect_dtype(const unsigned short* __restrict__ w, int* __restrict__ flag) {
    if (threadIdx.x == 0 && blockIdx.x == 0) {
        int f = 0;
        for (int i = 0; i < 512; ++i) {
            unsigned e = (w[i] >> 7) & 0xFF;
            if (e >= 127) f = 1;
        }
        *flag = f;
    }
}

// ---- prep: weights (bf16|f32) -> f16, bias sums -> f32, zero carries -----
__global__ void prep_w(const void* __restrict__ wih0, const void* __restrict__ whh0,
                       const void* __restrict__ bih0, const void* __restrict__ bhh0,
                       const void* __restrict__ wih1, const void* __restrict__ whh1,
                       const void* __restrict__ bih1, const void* __restrict__ bhh1,
                       _Float16* __restrict__ owih0, _Float16* __restrict__ owhh0,
                       _Float16* __restrict__ owih1, _Float16* __restrict__ owhh1,
                       float* __restrict__ obias0, float* __restrict__ obias1,
                       uint4* __restrict__ carries, const int* __restrict__ flag) {
    const bool f32 = (*flag != 0);
    int i = blockIdx.x * 256 + threadIdx.x;
    auto rd = [&](const void* p, int idx) -> float {
        return f32 ? ((const float*)p)[idx] : bf2f(((const unsigned short*)p)[idx]);
    };
    if (i < H_ * D_) owih0[i] = (_Float16)rd(wih0, i);
    if (i < H_ * H_) {
        owhh0[i] = (_Float16)rd(whh0, i);
        owih1[i] = (_Float16)rd(wih1, i);
        owhh1[i] = (_Float16)rd(whh1, i);
    }
    if (i < H_) {
        obias0[i] = rd(bih0, i) + rd(bhh0, i);
        obias1[i] = rd(bih1, i) + rd(bhh1, i);
    }
    if (i < (2 * B_ * H_) / 8) carries[i] = uint4{0, 0, 0, 0};
}

// ---- proj0 (768 thr, 48 rows/block): xw0 = x @ W_ih0^T + b0 --------------
__device__ __forceinline__ void proj0_dev(const void* __restrict__ x,
                                          const _Float16* __restrict__ W,
                                          const float* __restrict__ bias,
                                          _Float16* __restrict__ outx,
                                          const int* __restrict__ flag,
                                          int t0, int pb, char* __restrict__ sm,
                                          int tid) {
    const int sg = tid >> 8, j = tid & 255;   // 3 row-subgroups x 256 cols
    const long m0 = (long)pb * 48;
    const bool f32 = (*flag != 0);
    uint4* xt = (uint4*)sm;                   // [48][16] uint4 = 12 KB

    {   // stage: exactly one uint4 per thread (48*16 == 768)
        const int r = tid >> 4, c = tid & 15;
        const long m = m0 + r;
        uint4 v = uint4{0, 0, 0, 0};
        if (m < (long)B_ * TC) {
            long b = m / TC, tc = m - b * TC;
            long off = (b * T_ + t0 + tc) * (long)D_ + c * 8;
            if (f32) {
                const float* s = (const float*)x + off;
                union { _Float16 h[8]; uint4 u; } r8;
#pragma unroll
                for (int q = 0; q < 8; ++q) r8.h[q] = (_Float16)s[q];
                v = r8.u;
            } else {
                v = cvt8_bf16_to_f16(*(const uint4*)((const unsigned short*)x + off));
            }
        }
        xt[r * 16 + c] = v;
    }

    uint4 w[16];   // W row j, K=128
    const uint4* wp = (const uint4*)(W + (long)j * D_);
#pragma unroll
    for (int i = 0; i < 16; ++i) w[i] = wp[i];
    __syncthreads();

    const float bb = bias[j];
#pragma unroll 1
    for (int r = 0; r < 16; ++r) {
        const long m = m0 + sg * 16 + r;
        if (m < (long)B_ * TC) {
            const uint4* xr = xt + (sg * 16 + r) * 16;
            float a0 = 0.f, a1 = 0.f, a2 = 0.f, a3 = 0.f;
#pragma unroll
            for (int i = 0; i < 16; ++i) {
                uint4 h = xr[i];   // wave-uniform LDS broadcast
                uint4 ww = w[i];
                a0 = dot2(ww.x, h.x, a0);
                a1 = dot2(ww.y, h.y, a1);
                a2 = dot2(ww.z, h.z, a2);
                a3 = dot2(ww.w, h.w, a3);
            }
            outx[m * H_ + j] = (_Float16)(((a0 + a1) + (a2 + a3)) + bb);
        }
    }
}

// ---- fused two-layer scan (768 thr = 3 groups; v2-proven lag pipeline) ---
//   G0 (it<TC)     : h0[it]    = tanh(Whh0.h0buf[p] + xw0_lds[it])
//   G1 (1<=it<=TC) : xw1[it-1] = Wih1.h0buf[p] + b1          -> xw1buf[p^1]
//   G2 (it>=2)     : h1[it-2]  = tanh(Whh1.h1buf[p] + xw1buf[p]) -> LDS+global
__device__ __forceinline__ void fused_dev(const _Float16* __restrict__ xw0r,
                                          const _Float16* __restrict__ Whh0,
                                          const _Float16* __restrict__ Wih1,
                                          const _Float16* __restrict__ Whh1,
                                          const float* __restrict__ bias1,
                                          _Float16* __restrict__ carry0,
                                          _Float16* __restrict__ carry1,
                                          _Float16* __restrict__ h1w,
                                          char* __restrict__ sm, int b, int tid) {
    _Float16* stage = (_Float16*)sm;                     // [TC][256] 64 KB
    uint4* h0buf = (uint4*)(sm + TC * H_ * 2);           // [2][32]
    uint4* h1buf = h0buf + 64;                           // [2][32]
    float* xw1buf = (float*)(h1buf + 64);                // [2][256]

    const int g = tid >> 8, j = tid & 255;

    {   // stage the whole xw0 chunk: removes ALL global loads from the loop
        const uint4* src = (const uint4*)(xw0r + (long)b * TC * H_);
        uint4* dst = (uint4*)stage;
        for (int i = tid; i < TC * (H_ / 8); i += 768) dst[i] = src[i];
    }

    const _Float16* Wb = (g == 0) ? Whh0 : (g == 1) ? Wih1 : Whh1;
    uint4 w[32];   // weight row j (256 f16)
    const uint4* wp = (const uint4*)(Wb + (long)j * H_);
#pragma unroll
    for (int i = 0; i < 32; ++i) w[i] = wp[i];
    const float bb = (g == 1) ? bias1[j] : 0.f;

    if (g == 0) ((_Float16*)h0buf)[j] = carry0[b * H_ + j];
    if (g == 2) ((_Float16*)h1buf)[j] = carry1[b * H_ + j];
    __syncthreads();   // full drain once (covers stage + carry init)

    _Float16* hp = h1w + (long)b * TC * H_ + j;
    _Float16 h0last = (_Float16)0.f, h1last = (_Float16)0.f;

#pragma unroll 1
    for (int it = 0; it < TC + 2; ++it) {
        const int p = it & 1;
        if (g == 0) {
            if (it < TC) {
                float a = dot256(w, h0buf + p * 32);
                float hv = fast_tanh(a + (float)stage[it * H_ + j]);
                h0last = (_Float16)hv;
                ((_Float16*)(h0buf + (p ^ 1) * 32))[j] = h0last;
            }
        } else if (g == 1) {
            if (it >= 1 && it <= TC) {
                float a = dot256(w, h0buf + p * 32);
                xw1buf[(p ^ 1) * H_ + j] = a + bb;
            }
        } else {
            if (it >= 2) {
                float a = dot256(w, h1buf + p * 32);
                float hv = fast_tanh(a + xw1buf[p * H_ + j]);
                h1last = (_Float16)hv;
                ((_Float16*)(h1buf + (p ^ 1) * 32))[j] = h1last;
                hp[(long)(it - 2) * H_] = h1last;   // store floats across barrier
            }
        }
        lds_barrier();
    }

    if (g == 0) carry0[b * H_ + j] = h0last;
    if (g == 2) carry1[b * H_ + j] = h1last;
}

// ---- transpose (768 thr): h1 [b][tc][j] f16 -> out [b][j][t0+tc] ---------
__device__ __forceinline__ void transpose_dev(const _Float16* __restrict__ tmp,
                                              void* __restrict__ out,
                                              const int* __restrict__ flag,
                                              int t0, int pb, char* __restrict__ sm,
                                              int tid) {
    const int nTc = TC / 64;                  // 2
    int bid = pb;
    const int jblk = bid & 3; bid >>= 2;      // H_/64 == 4
    const int tcblk = bid % nTc;
    const int b = bid / nTc;
    const bool f32o = (*flag != 0);
    float* tile = (float*)sm;                 // [64][65]
#pragma unroll
    for (int k = 0; k < 6; ++k) {
        int idx = k * 768 + tid;
        if (idx < 4096) {
            int r = idx >> 6, c = idx & 63;
            int tc = tcblk * 64 + r;
            tile[r * 65 + c] = (float)tmp[((long)b * TC + tc) * H_ + jblk * 64 + c];
        }
    }
    __syncthreads();
#pragma unroll
    for (int k = 0; k < 6; ++k) {
        int idx = k * 768 + tid;
        if (idx < 4096) {
            int jr = idx >> 6, tc = idx & 63;
            float v = tile[tc * 65 + jr];
            long o = ((long)b * H_ + jblk * 64 + jr) * (long)T_ + t0 + tcblk * 64 + tc;
            if (f32o) ((float*)out)[o] = v;
            else      ((__hip_bfloat16*)out)[o] = __float2bfloat16(v);
        }
    }
}

// ---- boot: proj0 of chunk 0 ----------------------------------------------
__global__ __launch_bounds__(768, 1) void boot(
    const void* __restrict__ x, const _Float16* __restrict__ W,
    const float* __restrict__ bias, _Float16* __restrict__ outx,
    const int* __restrict__ flag)
{
    __shared__ __align__(16) char sm[12288];
    proj0_dev(x, W, bias, outx, flag, 0, blockIdx.x, sm, threadIdx.x);
}

// ---- mega: scan(d) || proj0(d+1) || transpose(d-1) -----------------------
__global__ __launch_bounds__(768, 1) void mega(
    const void* __restrict__ x,
    const _Float16* __restrict__ Wih0, const _Float16* __restrict__ Whh0,
    const _Float16* __restrict__ Wih1, const _Float16* __restrict__ Whh1,
    const float* __restrict__ bias0, const float* __restrict__ bias1,
    _Float16* __restrict__ carry0, _Float16* __restrict__ carry1,
    const _Float16* __restrict__ xw0r, _Float16* __restrict__ xw0w,
    _Float16* __restrict__ h1w, const _Float16* __restrict__ h1r,
    void* __restrict__ dout, const int* __restrict__ flag,
    int t_s, int t_p, int t_t, int nproj)
{
    __shared__ __align__(16) char sm[TC * H_ * 2 + 2048 + 2048];  // 69632 B
    const int bid = blockIdx.x;
    const int tid = threadIdx.x;

    if (bid < B_) {                              // fused scan chunk d
        if (t_s < 0) return;
        fused_dev(xw0r, Whh0, Wih1, Whh1, bias1, carry0, carry1, h1w, sm, bid, tid);
    } else if (bid < B_ + nproj) {               // proj0 chunk d+1
        if (t_p < 0) return;
        proj0_dev(x, Wih0, bias0, xw0w, flag, t_p, bid - B_, sm, tid);
    } else {                                     // transpose chunk d-1
        if (t_t < 0) return;
        transpose_dev(h1r, dout, flag, t_t, bid - B_ - nproj, sm, tid);
    }
}

// ---------------------------------------------------------------------------
extern "C" void kernel_launch(void* const* d_in, const int* in_sizes, int n_in,
                              void* d_out, int out_size, void* d_ws, size_t ws_size,
                              hipStream_t stream) {
    const void* x    = d_in[0];
    const void* wih0 = d_in[1];
    const void* whh0 = d_in[2];
    const void* bih0 = d_in[3];
    const void* bhh0 = d_in[4];
    const void* wih1 = d_in[5];
    const void* whh1 = d_in[6];
    const void* bih1 = d_in[7];
    const void* bhh1 = d_in[8];
    (void)in_sizes; (void)n_in; (void)out_size; (void)ws_size;

    char* ws = (char*)d_ws;
    size_t off = 0;
    auto alloc = [&](size_t bytes) -> void* {
        void* p = ws + off;
        off += (bytes + 255) & ~(size_t)255;
        return p;
    };

    int*      flag    = (int*)alloc(256);
    _Float16* wih0_16 = (_Float16*)alloc((size_t)H_ * D_ * 2);
    _Float16* whh0_16 = (_Float16*)alloc((size_t)H_ * H_ * 2);
    _Float16* wih1_16 = (_Float16*)alloc((size_t)H_ * H_ * 2);
    _Float16* whh1_16 = (_Float16*)alloc((size_t)H_ * H_ * 2);
    float*    bias0   = (float*)alloc(H_ * 4);
    float*    bias1   = (float*)alloc(H_ * 4);
    _Float16* carry0  = (_Float16*)alloc((size_t)B_ * H_ * 2);   // must stay
    _Float16* carry1  = (_Float16*)alloc((size_t)B_ * H_ * 2);   // adjacent

    // 4 chunk buffers x 4MB = 16MB (v1 proved ws >= ~17MB by running Tc=256)
    _Float16* xw0g[2];
    _Float16* h1g[2];
    xw0g[0] = (_Float16*)alloc((size_t)B_ * TC * H_ * 2);
    xw0g[1] = (_Float16*)alloc((size_t)B_ * TC * H_ * 2);
    h1g[0]  = (_Float16*)alloc((size_t)B_ * TC * H_ * 2);
    h1g[1]  = (_Float16*)alloc((size_t)B_ * TC * H_ * 2);

    detect_dtype<<<1, 64, 0, stream>>>((const unsigned short*)whh0, flag);
    prep_w<<<(H_ * H_ + 255) / 256, 256, 0, stream>>>(
        wih0, whh0, bih0, bhh0, wih1, whh1, bih1, bhh1,
        wih0_16, whh0_16, wih1_16, whh1_16, bias0, bias1, (uint4*)carry0, flag);

    const int NC     = T_ / TC;                       // 8
    const int nproj  = (B_ * TC + 47) / 48;           // 171
    const int ntrans = B_ * (TC / 64) * (H_ / 64);    // 512
    const int grid   = B_ + nproj + ntrans;

    boot<<<nproj, 768, 0, stream>>>(x, wih0_16, bias0, xw0g[0], flag);

    for (int d = 0; d <= NC; ++d) {
        const int t_s = (d < NC) ? d * TC : -1;               // scan chunk d
        const int t_p = (d + 1 < NC) ? (d + 1) * TC : -1;     // proj chunk d+1
        const int t_t = (d >= 1) ? (d - 1) * TC : -1;         // transpose d-1
        mega<<<grid, 768, 0, stream>>>(
            x, wih0_16, whh0_16, wih1_16, whh1_16, bias0, bias1,
            carry0, carry1,
            xw0g[d & 1],          // scan reads chunk d
            xw0g[(d + 1) & 1],    // proj0 writes chunk d+1
            h1g[d & 1],           // scan writes h1 chunk d
            h1g[(d - 1) & 1],     // transpose reads chunk d-1
            d_out, flag, t_s, t_p, t_t, nproj);
    }
}

// Round 7
// 1337.858 us; speedup vs baseline: 3.0853x; 1.1274x over previous
//
#include <hip/hip_runtime.h>
#include <hip/hip_bf16.h>

// ---------------------------------------------------------------------------
// RNN_20572893348005: 2-layer tanh RNN, B=64 T=1024 D=128 H=256, out [B,H,T]
//
// v8 = v7 mega structure + two scan-step fixes:
//  (1) CU exclusivity: static LDS 82176 B (>160KiB/2) -> 1 block/CU, so the
//      683 proj/transpose blocks can no longer co-schedule onto the 64
//      latency-critical scan CUs (v7's 2-blocks/CU regressed the step 15%).
//  (2) Split-K wave layout: lane l computes outputs 2(l&31),2(l&31)+1 over
//      K-half (l>>5); h-vector read = 16 ds_read_b128/wave (was 32), each
//      feeding TWO outputs; partials combined via 2x __shfl_xor(.,32).
//      Halves the dominant per-step LDS broadcast traffic; dot2 count and
//      4-chain ILP unchanged. h1 global stores now 4B x 32-lane contiguous.
// Dataflow identical to v7 (verified): 3-group lag pipeline (G0 h0-rec,
// G1 xw1-proj lag1, G2 h1-rec lag2), xw0 chunk staged in LDS, raw
// lgkmcnt-only barrier, mega roles scan(d)/proj0(d+1)/transpose(d-1).
// ---------------------------------------------------------------------------

#define B_ 64
#define T_ 1024
#define D_ 128
#define H_ 256
#define TC 128                 // time chunk (LDS stage = TC*H*2 = 64 KB)
#define SMEM_BYTES 82176       // > 81920 forces 1 block/CU (160 KiB LDS)

typedef _Float16 half2_t __attribute__((ext_vector_type(2)));

__device__ __forceinline__ float bf2f(unsigned short u) {
    union { unsigned int i; float f; } v;
    v.i = ((unsigned int)u) << 16;
    return v.f;
}

__device__ __forceinline__ unsigned int cvt2_bf16_to_f16(unsigned int u) {
    union { float f; unsigned int i; } a, b;
    a.i = u << 16;
    b.i = u & 0xFFFF0000u;
    union { _Float16 h[2]; unsigned int u; } r;
    r.h[0] = (_Float16)a.f;
    r.h[1] = (_Float16)b.f;
    return r.u;
}

__device__ __forceinline__ uint4 cvt8_bf16_to_f16(uint4 v) {
    uint4 r;
    r.x = cvt2_bf16_to_f16(v.x);
    r.y = cvt2_bf16_to_f16(v.y);
    r.z = cvt2_bf16_to_f16(v.z);
    r.w = cvt2_bf16_to_f16(v.w);
    return r;
}

__device__ __forceinline__ float dot2(unsigned int a, unsigned int b, float c) {
    union { unsigned int u; half2_t h; } ua, ub;
    ua.u = a; ub.u = b;
#if defined(__HIP_DEVICE_COMPILE__) && __has_builtin(__builtin_amdgcn_fdot2)
    return __builtin_amdgcn_fdot2(ua.h, ub.h, c, false);
#else
    return c + (float)ua.h.x * (float)ub.h.x + (float)ua.h.y * (float)ub.h.y;
#endif
}

// branch-free tanh: (e^{2x}-1)/(e^{2x}+1) via exp2 + rcp; saturates correctly.
__device__ __forceinline__ float fast_tanh(float x) {
#if defined(__HIP_DEVICE_COMPILE__) && __has_builtin(__builtin_amdgcn_exp2f)
    float e = __builtin_amdgcn_exp2f(x * 2.885390081777927f);
#else
    float e = __expf(2.0f * x);
#endif
#if defined(__HIP_DEVICE_COMPILE__) && __has_builtin(__builtin_amdgcn_rcpf)
    return 1.0f - 2.0f * __builtin_amdgcn_rcpf(e + 1.0f);
#else
    return 1.0f - 2.0f / (e + 1.0f);
#endif
}

// raw workgroup barrier: LDS ordering only (no vmcnt drain). v6/v7-proven.
__device__ __forceinline__ void lds_barrier() {
    asm volatile("s_waitcnt lgkmcnt(0)\n\ts_barrier" ::: "memory");
}

// split-K dual dot: two 128-long dot products (outputs j0,j0+1) sharing one
// 16x ds_read_b128 h-stream. 128 dot2, 4 chains of depth 32.
__device__ __forceinline__ void dot128x2(const uint4* __restrict__ w0,
                                         const uint4* __restrict__ w1,
                                         const uint4* __restrict__ hb,
                                         float& r0, float& r1) {
    float a0 = 0.f, a1 = 0.f, b0 = 0.f, b1 = 0.f;
#pragma unroll
    for (int i = 0; i < 16; ++i) {
        uint4 h = hb[i];   // 2 broadcast groups/wave (2-way: free)
        a0 = dot2(w0[i].x, h.x, a0); a1 = dot2(w0[i].y, h.y, a1);
        b0 = dot2(w1[i].x, h.x, b0); b1 = dot2(w1[i].y, h.y, b1);
        a0 = dot2(w0[i].z, h.z, a0); a1 = dot2(w0[i].w, h.w, a1);
        b0 = dot2(w1[i].z, h.z, b0); b1 = dot2(w1[i].w, h.w, b1);
    }
    r0 = a0 + a1;
    r1 = b0 + b1;
}

// ---- dtype detection ------------------------------------------------------
__global__ void detect_dtype(const unsigned short* __restrict__ w, int* __restrict__ flag) {
    if (threadIdx.x == 0 && blockIdx.x == 0) {
        int f = 0;
        for (int i = 0; i < 512; ++i) {
            unsigned e = (w[i] >> 7) & 0xFF;
            if (e >= 127) f = 1;
        }
        *flag = f;
    }
}

// ---- prep: weights (bf16|f32) -> f16, bias sums -> f32, zero carries -----
__global__ void prep_w(const void* __restrict__ wih0, const void* __restrict__ whh0,
                       const void* __restrict__ bih0, const void* __restrict__ bhh0,
                       const void* __restrict__ wih1, const void* __restrict__ whh1,
                       const void* __restrict__ bih1, const void* __restrict__ bhh1,
                       _Float16* __restrict__ owih0, _Float16* __restrict__ owhh0,
                       _Float16* __restrict__ owih1, _Float16* __restrict__ owhh1,
                       float* __restrict__ obias0, float* __restrict__ obias1,
                       uint4* __restrict__ carries, const int* __restrict__ flag) {
    const bool f32 = (*flag != 0);
    int i = blockIdx.x * 256 + threadIdx.x;
    auto rd = [&](const void* p, int idx) -> float {
        return f32 ? ((const float*)p)[idx] : bf2f(((const unsigned short*)p)[idx]);
    };
    if (i < H_ * D_) owih0[i] = (_Float16)rd(wih0, i);
    if (i < H_ * H_) {
        owhh0[i] = (_Float16)rd(whh0, i);
        owih1[i] = (_Float16)rd(wih1, i);
        owhh1[i] = (_Float16)rd(whh1, i);
    }
    if (i < H_) {
        obias0[i] = rd(bih0, i) + rd(bhh0, i);
        obias1[i] = rd(bih1, i) + rd(bhh1, i);
    }
    if (i < (2 * B_ * H_) / 8) carries[i] = uint4{0, 0, 0, 0};
}

// ---- proj0 (768 thr, 48 rows/block): xw0 = x @ W_ih0^T + b0 --------------
__device__ __forceinline__ void proj0_dev(const void* __restrict__ x,
                                          const _Float16* __restrict__ W,
                                          const float* __restrict__ bias,
                                          _Float16* __restrict__ outx,
                                          const int* __restrict__ flag,
                                          int t0, int pb, char* __restrict__ sm,
                                          int tid) {
    const int sg = tid >> 8, j = tid & 255;   // 3 row-subgroups x 256 cols
    const long m0 = (long)pb * 48;
    const bool f32 = (*flag != 0);
    uint4* xt = (uint4*)sm;                   // [48][16] uint4 = 12 KB

    {   // stage: exactly one uint4 per thread (48*16 == 768)
        const int r = tid >> 4, c = tid & 15;
        const long m = m0 + r;
        uint4 v = uint4{0, 0, 0, 0};
        if (m < (long)B_ * TC) {
            long b = m / TC, tc = m - b * TC;
            long off = (b * T_ + t0 + tc) * (long)D_ + c * 8;
            if (f32) {
                const float* s = (const float*)x + off;
                union { _Float16 h[8]; uint4 u; } r8;
#pragma unroll
                for (int q = 0; q < 8; ++q) r8.h[q] = (_Float16)s[q];
                v = r8.u;
            } else {
                v = cvt8_bf16_to_f16(*(const uint4*)((const unsigned short*)x + off));
            }
        }
        xt[r * 16 + c] = v;
    }

    uint4 w[16];   // W row j, K=128
    const uint4* wp = (const uint4*)(W + (long)j * D_);
#pragma unroll
    for (int i = 0; i < 16; ++i) w[i] = wp[i];
    __syncthreads();

    const float bb = bias[j];
#pragma unroll 1
    for (int r = 0; r < 16; ++r) {
        const long m = m0 + sg * 16 + r;
        if (m < (long)B_ * TC) {
            const uint4* xr = xt + (sg * 16 + r) * 16;
            float a0 = 0.f, a1 = 0.f, a2 = 0.f, a3 = 0.f;
#pragma unroll
            for (int i = 0; i < 16; ++i) {
                uint4 h = xr[i];   // wave-uniform LDS broadcast
                uint4 ww = w[i];
                a0 = dot2(ww.x, h.x, a0);
                a1 = dot2(ww.y, h.y, a1);
                a2 = dot2(ww.z, h.z, a2);
                a3 = dot2(ww.w, h.w, a3);
            }
            outx[m * H_ + j] = (_Float16)(((a0 + a1) + (a2 + a3)) + bb);
        }
    }
}

// ---- fused two-layer scan, split-K waves (v7 dataflow, v8 lane layout) ---
//   G0 (it<TC)     : h0[it]    = tanh(Whh0.h0buf[p] + xw0_lds[it])
//   G1 (1<=it<=TC) : xw1[it-1] = Wih1.h0buf[p] + b1          -> xw1buf[p^1]
//   G2 (it>=2)     : h1[it-2]  = tanh(Whh1.h1buf[p] + xw1buf[p]) -> LDS+global
// Wave covers 64 outputs: lane l -> outputs j0=2(l&31)(+1), K-half l>>5.
__device__ __forceinline__ void fused_dev(const _Float16* __restrict__ xw0r,
                                          const _Float16* __restrict__ Whh0,
                                          const _Float16* __restrict__ Wih1,
                                          const _Float16* __restrict__ Whh1,
                                          const float* __restrict__ bias1,
                                          _Float16* __restrict__ carry0,
                                          _Float16* __restrict__ carry1,
                                          _Float16* __restrict__ h1w,
                                          char* __restrict__ sm, int b, int tid) {
    _Float16* stage  = (_Float16*)sm;                  // [TC][256] 64 KB
    _Float16* h0buf  = (_Float16*)(sm + TC * H_ * 2);  // [2][256] f16
    _Float16* h1buf  = h0buf + 512;                    // [2][256] f16
    float*    xw1buf = (float*)(h1buf + 512);          // [2][256] f32

    const int g = tid >> 8, gt = tid & 255;
    const int wavid = gt >> 6, lane = tid & 63;
    const int half = lane >> 5;                        // K-half
    const int j0 = wavid * 64 + 2 * (lane & 31);       // outputs j0, j0+1
    const bool lo = (lane < 32);

    {   // stage the whole xw0 chunk: zero global loads in the loop
        const uint4* src = (const uint4*)(xw0r + (long)b * TC * H_);
        uint4* dst = (uint4*)stage;
        for (int i = tid; i < TC * (H_ / 8); i += 768) dst[i] = src[i];
    }

    const _Float16* Wb = (g == 0) ? Whh0 : (g == 1) ? Wih1 : Whh1;
    uint4 w0[16], w1[16];   // rows j0, j0+1, K-half `half` (128 f16 each)
    {
        const uint4* wp0 = (const uint4*)(Wb + (long)j0 * H_ + half * 128);
        const uint4* wp1 = (const uint4*)(Wb + (long)(j0 + 1) * H_ + half * 128);
#pragma unroll
        for (int i = 0; i < 16; ++i) { w0[i] = wp0[i]; w1[i] = wp1[i]; }
    }
    float bb0 = 0.f, bb1 = 0.f;
    if (g == 1) { bb0 = bias1[j0]; bb1 = bias1[j0 + 1]; }

    if (g == 0) h0buf[gt] = carry0[b * H_ + gt];
    if (g == 2) h1buf[gt] = carry1[b * H_ + gt];
    __syncthreads();   // full drain once (covers stage + carry init)

    _Float16* hp = h1w + (long)b * TC * H_;
    unsigned h0fin = 0, h1fin = 0;   // packed finals (lanes<32 valid)

#pragma unroll 1
    for (int it = 0; it < TC + 2; ++it) {
        const int p = it & 1;
        if (g == 0) {
            if (it < TC) {
                const uint4* hb = (const uint4*)(h0buf + p * 256) + half * 16;
                float s0, s1;
                dot128x2(w0, w1, hb, s0, s1);
                s0 += __shfl_xor(s0, 32, 64);
                s1 += __shfl_xor(s1, 32, 64);
                union { unsigned u; _Float16 h[2]; } xh;
                xh.u = *(const unsigned*)(stage + it * H_ + j0);
                union { _Float16 h[2]; unsigned u; } pk;
                pk.h[0] = (_Float16)fast_tanh(s0 + (float)xh.h[0]);
                pk.h[1] = (_Float16)fast_tanh(s1 + (float)xh.h[1]);
                if (lo) *(unsigned*)(h0buf + (p ^ 1) * 256 + j0) = pk.u;
                h0fin = pk.u;
            }
        } else if (g == 1) {
            if (it >= 1 && it <= TC) {
                const uint4* hb = (const uint4*)(h0buf + p * 256) + half * 16;
                float s0, s1;
                dot128x2(w0, w1, hb, s0, s1);
                s0 += __shfl_xor(s0, 32, 64);
                s1 += __shfl_xor(s1, 32, 64);
                if (lo) {
                    float2 v; v.x = s0 + bb0; v.y = s1 + bb1;
                    *(float2*)(xw1buf + (p ^ 1) * 256 + j0) = v;
                }
            }
        } else {
            if (it >= 2) {
                const uint4* hb = (const uint4*)(h1buf + p * 256) + half * 16;
                float s0, s1;
                dot128x2(w0, w1, hb, s0, s1);
                s0 += __shfl_xor(s0, 32, 64);
                s1 += __shfl_xor(s1, 32, 64);
                float2 xv = *(const float2*)(xw1buf + p * 256 + j0);
                union { _Float16 h[2]; unsigned u; } pk;
                pk.h[0] = (_Float16)fast_tanh(s0 + xv.x);
                pk.h[1] = (_Float16)fast_tanh(s1 + xv.y);
                if (lo) {
                    *(unsigned*)(h1buf + (p ^ 1) * 256 + j0) = pk.u;
                    // 4B x 32-lane contiguous; floats across the raw barrier
                    *(unsigned*)(hp + (long)(it - 2) * H_ + j0) = pk.u;
                }
                h1fin = pk.u;
            }
        }
        lds_barrier();
    }

    if (g == 0 && lo) *(unsigned*)(carry0 + (long)b * H_ + j0) = h0fin;
    if (g == 2 && lo) *(unsigned*)(carry1 + (long)b * H_ + j0) = h1fin;
}

// ---- transpose (768 thr): h1 [b][tc][j] f16 -> out [b][j][t0+tc] ---------
__device__ __forceinline__ void transpose_dev(const _Float16* __restrict__ tmp,
                                              void* __restrict__ out,
                                              const int* __restrict__ flag,
                                              int t0, int pb, char* __restrict__ sm,
                                              int tid) {
    const int nTc = TC / 64;                  // 2
    int bid = pb;
    const int jblk = bid & 3; bid >>= 2;      // H_/64 == 4
    const int tcblk = bid % nTc;
    const int b = bid / nTc;
    const bool f32o = (*flag != 0);
    float* tile = (float*)sm;                 // [64][65]
#pragma unroll
    for (int k = 0; k < 6; ++k) {
        int idx = k * 768 + tid;
        if (idx < 4096) {
            int r = idx >> 6, c = idx & 63;
            int tc = tcblk * 64 + r;
            tile[r * 65 + c] = (float)tmp[((long)b * TC + tc) * H_ + jblk * 64 + c];
        }
    }
    __syncthreads();
#pragma unroll
    for (int k = 0; k < 6; ++k) {
        int idx = k * 768 + tid;
        if (idx < 4096) {
            int jr = idx >> 6, tc = idx & 63;
            float v = tile[tc * 65 + jr];
            long o = ((long)b * H_ + jblk * 64 + jr) * (long)T_ + t0 + tcblk * 64 + tc;
            if (f32o) ((float*)out)[o] = v;
            else      ((__hip_bfloat16*)out)[o] = __float2bfloat16(v);
        }
    }
}

// ---- boot: proj0 of chunk 0 ----------------------------------------------
__global__ __launch_bounds__(768, 1) void boot(
    const void* __restrict__ x, const _Float16* __restrict__ W,
    const float* __restrict__ bias, _Float16* __restrict__ outx,
    const int* __restrict__ flag)
{
    __shared__ __align__(16) char sm[12288];
    proj0_dev(x, W, bias, outx, flag, 0, blockIdx.x, sm, threadIdx.x);
}

// ---- mega: scan(d) || proj0(d+1) || transpose(d-1) -----------------------
__global__ __launch_bounds__(768, 1) void mega(
    const void* __restrict__ x,
    const _Float16* __restrict__ Wih0, const _Float16* __restrict__ Whh0,
    const _Float16* __restrict__ Wih1, const _Float16* __restrict__ Whh1,
    const float* __restrict__ bias0, const float* __restrict__ bias1,
    _Float16* __restrict__ carry0, _Float16* __restrict__ carry1,
    const _Float16* __restrict__ xw0r, _Float16* __restrict__ xw0w,
    _Float16* __restrict__ h1w, const _Float16* __restrict__ h1r,
    void* __restrict__ dout, const int* __restrict__ flag,
    int t_s, int t_p, int t_t, int nproj)
{
    // > 80 KiB: forces 1 block/CU so proj/transpose never co-schedule onto
    // the latency-critical scan CUs (v7's regression).
    __shared__ __align__(16) char sm[SMEM_BYTES];
    const int bid = blockIdx.x;
    const int tid = threadIdx.x;

    if (bid < B_) {                              // fused scan chunk d
        if (t_s < 0) return;
        fused_dev(xw0r, Whh0, Wih1, Whh1, bias1, carry0, carry1, h1w, sm, bid, tid);
    } else if (bid < B_ + nproj) {               // proj0 chunk d+1
        if (t_p < 0) return;
        proj0_dev(x, Wih0, bias0, xw0w, flag, t_p, bid - B_, sm, tid);
    } else {                                     // transpose chunk d-1
        if (t_t < 0) return;
        transpose_dev(h1r, dout, flag, t_t, bid - B_ - nproj, sm, tid);
    }
}

// ---------------------------------------------------------------------------
extern "C" void kernel_launch(void* const* d_in, const int* in_sizes, int n_in,
                              void* d_out, int out_size, void* d_ws, size_t ws_size,
                              hipStream_t stream) {
    const void* x    = d_in[0];
    const void* wih0 = d_in[1];
    const void* whh0 = d_in[2];
    const void* bih0 = d_in[3];
    const void* bhh0 = d_in[4];
    const void* wih1 = d_in[5];
    const void* whh1 = d_in[6];
    const void* bih1 = d_in[7];
    const void* bhh1 = d_in[8];
    (void)in_sizes; (void)n_in; (void)out_size; (void)ws_size;

    char* ws = (char*)d_ws;
    size_t off = 0;
    auto alloc = [&](size_t bytes) -> void* {
        void* p = ws + off;
        off += (bytes + 255) & ~(size_t)255;
        return p;
    };

    int*      flag    = (int*)alloc(256);
    _Float16* wih0_16 = (_Float16*)alloc((size_t)H_ * D_ * 2);
    _Float16* whh0_16 = (_Float16*)alloc((size_t)H_ * H_ * 2);
    _Float16* wih1_16 = (_Float16*)alloc((size_t)H_ * H_ * 2);
    _Float16* whh1_16 = (_Float16*)alloc((size_t)H_ * H_ * 2);
    float*    bias0   = (float*)alloc(H_ * 4);
    float*    bias1   = (float*)alloc(H_ * 4);
    _Float16* carry0  = (_Float16*)alloc((size_t)B_ * H_ * 2);   // must stay
    _Float16* carry1  = (_Float16*)alloc((size_t)B_ * H_ * 2);   // adjacent

    _Float16* xw0g[2];
    _Float16* h1g[2];
    xw0g[0] = (_Float16*)alloc((size_t)B_ * TC * H_ * 2);
    xw0g[1] = (_Float16*)alloc((size_t)B_ * TC * H_ * 2);
    h1g[0]  = (_Float16*)alloc((size_t)B_ * TC * H_ * 2);
    h1g[1]  = (_Float16*)alloc((size_t)B_ * TC * H_ * 2);

    detect_dtype<<<1, 64, 0, stream>>>((const unsigned short*)whh0, flag);
    prep_w<<<(H_ * H_ + 255) / 256, 256, 0, stream>>>(
        wih0, whh0, bih0, bhh0, wih1, whh1, bih1, bhh1,
        wih0_16, whh0_16, wih1_16, whh1_16, bias0, bias1, (uint4*)carry0, flag);

    const int NC     = T_ / TC;                       // 8
    const int nproj  = (B_ * TC + 47) / 48;           // 171
    const int ntrans = B_ * (TC / 64) * (H_ / 64);    // 512
    const int grid   = B_ + nproj + ntrans;

    boot<<<nproj, 768, 0, stream>>>(x, wih0_16, bias0, xw0g[0], flag);

    for (int d = 0; d <= NC; ++d) {
        const int t_s = (d < NC) ? d * TC : -1;               // scan chunk d
        const int t_p = (d + 1 < NC) ? (d + 1) * TC : -1;     // proj chunk d+1
        const int t_t = (d >= 1) ? (d - 1) * TC : -1;         // transpose d-1
        mega<<<grid, 768, 0, stream>>>(
            x, wih0_16, whh0_16, wih1_16, whh1_16, bias0, bias1,
            carry0, carry1,
            xw0g[d & 1],          // scan reads chunk d
            xw0g[(d + 1) & 1],    // proj0 writes chunk d+1
            h1g[d & 1],           // scan writes h1 chunk d
            h1g[(d - 1) & 1],     // transpose reads chunk d-1
            d_out, flag, t_s, t_p, t_t, nproj);
    }
}

// Round 9
// 871.990 us; speedup vs baseline: 4.7337x; 1.5343x over previous
//
#include <hip/hip_runtime.h>
#include <hip/hip_bf16.h>

// ---------------------------------------------------------------------------
// RNN_20572893348005: 2-layer tanh RNN, B=64 T=1024 D=128 H=256, out [B,H,T]
//
// v10 = v9 with the barrier hazard fixed: in v9, scan waves 8-11 exited
// before the per-step raw s_barrier loop (first kernel to mix exited waves
// with s_barrier -> plausible HW deadlock -> container timeout x2).
// Now ALL 768 threads stay alive through scan_layer: staging + bulk copy
// use 12 waves; per-step compute predicated on tid<512; idle waves execute
// the same Tc barriers. Design otherwise identical to v9:
//   blocks 0-63   : scan0 chunk d      (512 compute thr: 1 output/lane,
//   blocks 64-127 : scan1 chunk d-2     2-way K-split, 64 weight VGPRs)
//   blocks 128+   : proj0(d+1) GEMM, proj1(d-1) GEMM, transpose(d-3)
// Scan step: 16 broadcast ds_read_b128 (2-addr = free), 64 dot2 (4 chains),
// 1 shfl_xor(32), tanh; h-chunk overwrites consumed xw slot in LDS stage
// (zero per-step global stores; bulk coalesced copy at end); raw
// lgkmcnt-only barrier; s_setprio(1) vs co-scheduled GEMM blocks.
// ---------------------------------------------------------------------------

#define B_ 64
#define T_ 1024
#define D_ 128
#define H_ 256
#define TCMAX 128              // LDS stage = TCMAX*H*2 = 64 KB

typedef _Float16 half2_t __attribute__((ext_vector_type(2)));

__device__ __forceinline__ float bf2f(unsigned short u) {
    union { unsigned int i; float f; } v;
    v.i = ((unsigned int)u) << 16;
    return v.f;
}

__device__ __forceinline__ unsigned int cvt2_bf16_to_f16(unsigned int u) {
    union { float f; unsigned int i; } a, b;
    a.i = u << 16;
    b.i = u & 0xFFFF0000u;
    union { _Float16 h[2]; unsigned int u; } r;
    r.h[0] = (_Float16)a.f;
    r.h[1] = (_Float16)b.f;
    return r.u;
}

__device__ __forceinline__ uint4 cvt8_bf16_to_f16(uint4 v) {
    uint4 r;
    r.x = cvt2_bf16_to_f16(v.x);
    r.y = cvt2_bf16_to_f16(v.y);
    r.z = cvt2_bf16_to_f16(v.z);
    r.w = cvt2_bf16_to_f16(v.w);
    return r;
}

__device__ __forceinline__ float dot2(unsigned int a, unsigned int b, float c) {
    union { unsigned int u; half2_t h; } ua, ub;
    ua.u = a; ub.u = b;
#if defined(__HIP_DEVICE_COMPILE__) && __has_builtin(__builtin_amdgcn_fdot2)
    return __builtin_amdgcn_fdot2(ua.h, ub.h, c, false);
#else
    return c + (float)ua.h.x * (float)ub.h.x + (float)ua.h.y * (float)ub.h.y;
#endif
}

// branch-free tanh: (e^{2x}-1)/(e^{2x}+1) via exp2 + rcp; saturates correctly.
__device__ __forceinline__ float fast_tanh(float x) {
#if defined(__HIP_DEVICE_COMPILE__) && __has_builtin(__builtin_amdgcn_exp2f)
    float e = __builtin_amdgcn_exp2f(x * 2.885390081777927f);
#else
    float e = __expf(2.0f * x);
#endif
#if defined(__HIP_DEVICE_COMPILE__) && __has_builtin(__builtin_amdgcn_rcpf)
    return 1.0f - 2.0f * __builtin_amdgcn_rcpf(e + 1.0f);
#else
    return 1.0f - 2.0f / (e + 1.0f);
#endif
}

// raw workgroup barrier: LDS ordering only (no vmcnt drain). v6-v8-proven.
// Executed by ALL waves of the block (no exited waves - the v9 hazard).
__device__ __forceinline__ void lds_barrier() {
    asm volatile("s_waitcnt lgkmcnt(0)\n\ts_barrier" ::: "memory");
}

// ---- dtype detection ------------------------------------------------------
__global__ void detect_dtype(const unsigned short* __restrict__ w, int* __restrict__ flag) {
    if (threadIdx.x == 0 && blockIdx.x == 0) {
        int f = 0;
        for (int i = 0; i < 512; ++i) {
            unsigned e = (w[i] >> 7) & 0xFF;
            if (e >= 127) f = 1;
        }
        *flag = f;
    }
}

// ---- prep: weights (bf16|f32) -> f16, bias sums -> f32, zero carries -----
__global__ void prep_w(const void* __restrict__ wih0, const void* __restrict__ whh0,
                       const void* __restrict__ bih0, const void* __restrict__ bhh0,
                       const void* __restrict__ wih1, const void* __restrict__ whh1,
                       const void* __restrict__ bih1, const void* __restrict__ bhh1,
                       _Float16* __restrict__ owih0, _Float16* __restrict__ owhh0,
                       _Float16* __restrict__ owih1, _Float16* __restrict__ owhh1,
                       float* __restrict__ obias0, float* __restrict__ obias1,
                       uint4* __restrict__ carries, const int* __restrict__ flag) {
    const bool f32 = (*flag != 0);
    int i = blockIdx.x * 256 + threadIdx.x;
    auto rd = [&](const void* p, int idx) -> float {
        return f32 ? ((const float*)p)[idx] : bf2f(((const unsigned short*)p)[idx]);
    };
    if (i < H_ * D_) owih0[i] = (_Float16)rd(wih0, i);
    if (i < H_ * H_) {
        owhh0[i] = (_Float16)rd(whh0, i);
        owih1[i] = (_Float16)rd(wih1, i);
        owhh1[i] = (_Float16)rd(whh1, i);
    }
    if (i < H_) {
        obias0[i] = rd(bih0, i) + rd(bhh0, i);
        obias1[i] = rd(bih1, i) + rd(bhh1, i);
    }
    if (i < (2 * B_ * H_) / 8) carries[i] = uint4{0, 0, 0, 0};
}

// ---- projection GEMM (768 thr, 48 rows/block): out = src @ W^T + bias ----
template <int K, bool XSRC>
__device__ __forceinline__ void proj_gemm(const void* __restrict__ src,
                                          const _Float16* __restrict__ W,
                                          const float* __restrict__ bias,
                                          _Float16* __restrict__ outx,
                                          const int* __restrict__ flag,
                                          int t0, int Tc, int pb,
                                          char* __restrict__ sm, int tid) {
    constexpr int KW = K / 8;  // uint4 (8 f16) per row
    const int sg = tid >> 8, j = tid & 255;   // 3 row-subgroups x 256 cols
    const long m0 = (long)pb * 48;
    const bool f32 = XSRC && (*flag != 0);
    uint4* xt = (uint4*)sm;                   // [48][KW] (<= 24 KB)

    for (int idx = tid; idx < 48 * KW; idx += 768) {
        int r = idx / KW, c = idx % KW;
        long m = m0 + r;
        uint4 v = uint4{0, 0, 0, 0};
        if (m < (long)B_ * Tc) {
            long off;
            if (XSRC) {
                long b = m / Tc, tc = m - b * Tc;
                off = (b * T_ + t0 + tc) * (long)K + (long)c * 8;
                if (f32) {
                    const float* s = (const float*)src + off;
                    union { _Float16 h[8]; uint4 u; } r8;
#pragma unroll
                    for (int q = 0; q < 8; ++q) r8.h[q] = (_Float16)s[q];
                    v = r8.u;
                } else {
                    v = cvt8_bf16_to_f16(*(const uint4*)((const unsigned short*)src + off));
                }
            } else {
                off = m * (long)K + (long)c * 8;
                v = *(const uint4*)((const _Float16*)src + off);
            }
        }
        xt[idx] = v;
    }

    uint4 w[KW];   // W row j
    const uint4* wp = (const uint4*)(W + (long)j * K);
#pragma unroll
    for (int i = 0; i < KW; ++i) w[i] = wp[i];
    __syncthreads();

    const float bb = bias[j];
#pragma unroll 1
    for (int r = 0; r < 16; ++r) {
        const long m = m0 + sg * 16 + r;
        if (m < (long)B_ * Tc) {
            const uint4* xr = xt + (sg * 16 + r) * KW;
            float a0 = 0.f, a1 = 0.f, a2 = 0.f, a3 = 0.f;
#pragma unroll
            for (int i = 0; i < KW; ++i) {
                uint4 h = xr[i];   // wave-uniform LDS broadcast
                uint4 ww = w[i];
                a0 = dot2(ww.x, h.x, a0);
                a1 = dot2(ww.y, h.y, a1);
                a2 = dot2(ww.z, h.z, a2);
                a3 = dot2(ww.w, h.w, a3);
            }
            outx[m * H_ + j] = (_Float16)(((a0 + a1) + (a2 + a3)) + bb);
        }
    }
}

// ---- single-layer scan: h[t] = tanh(Whh h[t-1] + xw[t]) ------------------
// 512 compute threads = 8 waves; lane -> output jj = wv*32+(lane&31),
// K-half = lane>>5. Weights = 128 f16 = 64 VGPRs (arch-residency target).
// Waves 8-11 idle but execute the SAME barrier sequence (no exited waves).
// h-chunk overwrites consumed xw slot in the LDS stage (half==1 lane);
// bulk coalesced global copy after the loop.
__device__ __forceinline__ void scan_layer(const _Float16* __restrict__ xw,
                                           const _Float16* __restrict__ Whh,
                                           _Float16* __restrict__ carry,
                                           _Float16* __restrict__ hout,
                                           char* __restrict__ sm, int b,
                                           int tid, int Tc) {
    __builtin_amdgcn_s_setprio(1);                // beat co-scheduled GEMM waves
    _Float16* stage = (_Float16*)sm;              // [Tc][256] (<= 64 KB)
    _Float16* hbuf  = (_Float16*)(sm + TCMAX * H_ * 2);  // [2][256]
    const bool act = (tid < 512);
    const int wv = tid >> 6, lane = tid & 63, half = lane >> 5;
    const int jj = (wv & 7) * 32 + (lane & 31);

    uint4 w[16];   // 128 f16: row jj, K-half (loaded by compute threads only)
    if (act) {
        const uint4* wp = (const uint4*)(Whh + (long)jj * H_ + half * 128);
#pragma unroll
        for (int i = 0; i < 16; ++i) w[i] = wp[i];
    }

    {   // stage the whole xw chunk (all 12 waves): zero global loads in loop
        const uint4* src = (const uint4*)(xw + (long)b * Tc * H_);
        uint4* dst = (uint4*)stage;
        for (int i = tid; i < Tc * (H_ / 8); i += 768) dst[i] = src[i];
    }
    if (tid < 256) hbuf[tid] = carry[b * H_ + tid];
    __syncthreads();   // full drain once (stage loads + carry init)

    float hlast = 0.f;
#pragma unroll 1
    for (int it = 0; it < Tc; ++it) {
        const int p = it & 1;
        if (act) {
            float xh = (float)stage[it * H_ + jj];     // broadcast pair read
            const uint4* hb = (const uint4*)(hbuf + p * H_) + half * 16;
            float a0 = 0.f, a1 = 0.f, a2 = 0.f, a3 = 0.f;
#pragma unroll
            for (int i = 0; i < 16; ++i) {
                uint4 h = hb[i];   // 2-addr broadcast read: conflict-free
                uint4 ww = w[i];
                a0 = dot2(ww.x, h.x, a0);
                a1 = dot2(ww.y, h.y, a1);
                a2 = dot2(ww.z, h.z, a2);
                a3 = dot2(ww.w, h.w, a3);
            }
            float s = (a0 + a1) + (a2 + a3);
            s += __shfl_xor(s, 32, 64);
            float hv = fast_tanh(s + xh);
            _Float16 hf = (_Float16)hv;
            if (half == 0) hbuf[(p ^ 1) * H_ + jj] = hf;  // state for next step
            else           stage[it * H_ + jj]     = hf;  // h in place of xw
            hlast = hv;
        }
        lds_barrier();   // ALL waves, every iteration
    }

    if (act && half == 0) carry[b * H_ + jj] = (_Float16)hlast;
    {   // bulk coalesced h-chunk write (all 12 waves, off the critical path)
        const uint4* src = (const uint4*)stage;
        uint4* dst = (uint4*)(hout + (long)b * Tc * H_);
        for (int i = tid; i < Tc * (H_ / 8); i += 768) dst[i] = src[i];
    }
}

// ---- transpose (768 thr): h1 [b][tc][j] f16 -> out [b][j][t0+tc] ---------
__device__ __forceinline__ void transpose_dev(const _Float16* __restrict__ tmp,
                                              void* __restrict__ out,
                                              const int* __restrict__ flag,
                                              int t0, int Tc, int pb,
                                              char* __restrict__ sm, int tid) {
    const int nTc = (Tc + 63) >> 6;
    int bid = pb;
    const int jblk = bid & 3; bid >>= 2;      // H_/64 == 4
    const int tcblk = bid % nTc;
    const int b = bid / nTc;
    const bool f32o = (*flag != 0);
    float* tile = (float*)sm;                 // [64][65]
#pragma unroll
    for (int k = 0; k < 6; ++k) {
        int idx = k * 768 + tid;
        if (idx < 4096) {
            int r = idx >> 6, c = idx & 63;
            int tc = tcblk * 64 + r;
            tile[r * 65 + c] = (tc < Tc)
                ? (float)tmp[((long)b * Tc + tc) * H_ + jblk * 64 + c] : 0.f;
        }
    }
    __syncthreads();
#pragma unroll
    for (int k = 0; k < 6; ++k) {
        int idx = k * 768 + tid;
        if (idx < 4096) {
            int jr = idx >> 6, tc = idx & 63;
            if (tcblk * 64 + tc < Tc) {
                float v = tile[tc * 65 + jr];
                long o = ((long)b * H_ + jblk * 64 + jr) * (long)T_ + t0 + tcblk * 64 + tc;
                if (f32o) ((float*)out)[o] = v;
                else      ((__hip_bfloat16*)out)[o] = __float2bfloat16(v);
            }
        }
    }
}

// ---- boot: proj0 of chunk 0 ----------------------------------------------
__global__ __launch_bounds__(768, 1) void boot(
    const void* __restrict__ x, const _Float16* __restrict__ W,
    const float* __restrict__ bias, _Float16* __restrict__ outx,
    const int* __restrict__ flag, int Tc)
{
    __shared__ __align__(16) char sm[24576];
    proj_gemm<D_, true>(x, W, bias, outx, flag, 0, Tc, blockIdx.x, sm, threadIdx.x);
}

// ---- mega: scan0(d) || scan1(d-2) || proj0(d+1) || proj1(d-1) || tr(d-3) -
__global__ __launch_bounds__(768, 1) void mega(
    const void* __restrict__ x,
    const _Float16* __restrict__ Wih0, const _Float16* __restrict__ Whh0,
    const _Float16* __restrict__ Wih1, const _Float16* __restrict__ Whh1,
    const float* __restrict__ bias0, const float* __restrict__ bias1,
    _Float16* __restrict__ carry0, _Float16* __restrict__ carry1,
    const _Float16* __restrict__ xw0r, _Float16* __restrict__ xw0w,
    _Float16* __restrict__ h0w, const _Float16* __restrict__ h0r,
    _Float16* __restrict__ xw1w, const _Float16* __restrict__ xw1r,
    _Float16* __restrict__ h1w, const _Float16* __restrict__ h1r,
    void* __restrict__ dout, const int* __restrict__ flag,
    int v_s0, int t_p0, int v_p1, int v_s1, int t_tr, int Tc, int nproj)
{
    __shared__ __align__(16) char sm[TCMAX * H_ * 2 + 1024];  // 66560 B
    const int bid = blockIdx.x;
    const int tid = threadIdx.x;

    if (bid < 64) {                              // scan0 chunk d
        if (!v_s0) return;
        scan_layer(xw0r, Whh0, carry0, h0w, sm, bid, tid, Tc);
    } else if (bid < 128) {                      // scan1 chunk d-2
        if (!v_s1) return;
        scan_layer(xw1r, Whh1, carry1, h1w, sm, bid - 64, tid, Tc);
    } else if (bid < 128 + nproj) {              // proj0 chunk d+1
        if (t_p0 < 0) return;
        proj_gemm<D_, true>(x, Wih0, bias0, xw0w, flag, t_p0, Tc, bid - 128, sm, tid);
    } else if (bid < 128 + 2 * nproj) {          // proj1 chunk d-1
        if (!v_p1) return;
        proj_gemm<H_, false>(h0r, Wih1, bias1, xw1w, flag, 0, Tc, bid - 128 - nproj, sm, tid);
    } else {                                     // transpose chunk d-3
        if (t_tr < 0) return;
        transpose_dev(h1r, dout, flag, t_tr, Tc, bid - 128 - 2 * nproj, sm, tid);
    }
}

// ---------------------------------------------------------------------------
extern "C" void kernel_launch(void* const* d_in, const int* in_sizes, int n_in,
                              void* d_out, int out_size, void* d_ws, size_t ws_size,
                              hipStream_t stream) {
    const void* x    = d_in[0];
    const void* wih0 = d_in[1];
    const void* whh0 = d_in[2];
    const void* bih0 = d_in[3];
    const void* bhh0 = d_in[4];
    const void* wih1 = d_in[5];
    const void* whh1 = d_in[6];
    const void* bih1 = d_in[7];
    const void* bhh1 = d_in[8];
    (void)in_sizes; (void)n_in; (void)out_size;

    char* ws = (char*)d_ws;
    size_t off = 0;
    auto alloc = [&](size_t bytes) -> void* {
        void* p = ws + off;
        off += (bytes + 255) & ~(size_t)255;
        return p;
    };

    int*      flag    = (int*)alloc(256);
    _Float16* wih0_16 = (_Float16*)alloc((size_t)H_ * D_ * 2);
    _Float16* whh0_16 = (_Float16*)alloc((size_t)H_ * H_ * 2);
    _Float16* wih1_16 = (_Float16*)alloc((size_t)H_ * H_ * 2);
    _Float16* whh1_16 = (_Float16*)alloc((size_t)H_ * H_ * 2);
    float*    bias0   = (float*)alloc(H_ * 4);
    float*    bias1   = (float*)alloc(H_ * 4);
    _Float16* carry0  = (_Float16*)alloc((size_t)B_ * H_ * 2);   // must stay
    _Float16* carry1  = (_Float16*)alloc((size_t)B_ * H_ * 2);   // adjacent

    size_t fixed = off;
    // largest Tc (<=TCMAX) whose EIGHT chunk buffers fit in ws
    int Tc = TCMAX;
    while (Tc > 32 && fixed + 8 * ((size_t)B_ * Tc * H_ * 2 + 256) > ws_size) Tc >>= 1;
    _Float16 *xw0g[2], *xw1g[2], *h0g[2], *h1g[2];
    for (int i = 0; i < 2; ++i) xw0g[i] = (_Float16*)alloc((size_t)B_ * Tc * H_ * 2);
    for (int i = 0; i < 2; ++i) xw1g[i] = (_Float16*)alloc((size_t)B_ * Tc * H_ * 2);
    for (int i = 0; i < 2; ++i) h0g[i]  = (_Float16*)alloc((size_t)B_ * Tc * H_ * 2);
    for (int i = 0; i < 2; ++i) h1g[i]  = (_Float16*)alloc((size_t)B_ * Tc * H_ * 2);

    detect_dtype<<<1, 64, 0, stream>>>((const unsigned short*)whh0, flag);
    prep_w<<<(H_ * H_ + 255) / 256, 256, 0, stream>>>(
        wih0, whh0, bih0, bhh0, wih1, whh1, bih1, bhh1,
        wih0_16, whh0_16, wih1_16, whh1_16, bias0, bias1, (uint4*)carry0, flag);

    const int NC     = T_ / Tc;
    const int nproj  = (B_ * Tc + 47) / 48;
    const int ntrans = B_ * ((Tc + 63) / 64) * (H_ / 64);
    const int grid   = 128 + 2 * nproj + ntrans;

    boot<<<nproj, 768, 0, stream>>>(x, wih0_16, bias0, xw0g[0], flag, Tc);

    for (int d = 0; d <= NC + 2; ++d) {
        const int v_s0 = (d < NC) ? 1 : 0;                       // scan0 chunk d
        const int t_p0 = (d + 1 < NC) ? (d + 1) * Tc : -1;       // proj0 chunk d+1
        const int v_p1 = (d - 1 >= 0 && d - 1 < NC) ? 1 : 0;     // proj1 chunk d-1
        const int v_s1 = (d - 2 >= 0 && d - 2 < NC) ? 1 : 0;     // scan1 chunk d-2
        const int t_tr = (d - 3 >= 0 && d - 3 < NC) ? (d - 3) * Tc : -1;
        mega<<<grid, 768, 0, stream>>>(
            x, wih0_16, whh0_16, wih1_16, whh1_16, bias0, bias1,
            carry0, carry1,
            xw0g[d & 1],            // scan0 reads chunk d
            xw0g[(d + 1) & 1],      // proj0 writes chunk d+1
            h0g[d & 1],             // scan0 writes chunk d
            h0g[(d - 1) & 1],       // proj1 reads chunk d-1
            xw1g[(d - 1) & 1],      // proj1 writes chunk d-1
            xw1g[(d - 2) & 1],      // scan1 reads chunk d-2
            h1g[(d - 2) & 1],       // scan1 writes chunk d-2
            h1g[(d - 3) & 1],       // transpose reads chunk d-3
            d_out, flag, v_s0, t_p0, v_p1, v_s1, t_tr, Tc, nproj);
    }
}